// Round 3
// baseline (3250.768 us; speedup 1.0000x reference)
//
#include <hip/hip_runtime.h>

#define J 27
#define D 512
#define H 8
#define DH 64
#define NLAYER 6
#define DFF 2048
#define NB 64
#define NP 2048
#define CAP 128
#define GCH 16
#define GPTS 128
#define NEGF -1000000000.0f

__constant__ int c_parent[J] = {0,0,1,2,3,4,5,6,7,8,8,3,11,12,13,14,15,15,0,18,19,20,0,22,23,24,3};
__constant__ float c_scale[J] = {0.6f,0.6f,0.6f,0.6f,1.f,1.f,1.f,1.f,1.f,1.5f,1.5f,1.f,1.f,1.f,1.f,1.f,
                                 1.5f,1.5f,0.6f,1.f,1.5f,1.5f,0.6f,1.f,1.5f,1.5f,1.5f};

__device__ __forceinline__ float siluf(float x){ return x/(1.f+expf(-x)); }

typedef __attribute__((ext_vector_type(8))) __bf16 bf16x8;
typedef __attribute__((ext_vector_type(4))) float f32x4;

// split a pair of floats into packed (hi,hi) and (lo,lo) bf16 words.
// hi = truncate-to-bf16(a) (exact residual), lo = truncate-to-bf16(a-hi).
// representation error ~2^-16 relative — 3-term MFMA keeps fp32-like accuracy.
__device__ __forceinline__ void split2(float a0, float a1, unsigned &hi, unsigned &lo){
  union { float f; unsigned u; } x0, x1, h0, h1, y0, y1;
  x0.f = a0; x1.f = a1;
  h0.u = x0.u & 0xffff0000u;
  h1.u = x1.u & 0xffff0000u;
  y0.f = a0 - h0.f;
  y1.f = a1 - h1.f;
  hi = (x0.u >> 16) | (x1.u & 0xffff0000u);
  lo = (y0.u >> 16) | (y1.u & 0xffff0000u);
}

// ---------- per (b,j): denom sum, rescue idx (argmin dist), allmask, active-bitmap marks ----------
__global__ void k_perj(const float* __restrict__ x_t, const float* __restrict__ pc,
                       float* __restrict__ denom_sum, int* __restrict__ rescue,
                       int* __restrict__ allm, unsigned int* __restrict__ bitmap){
  int bj = blockIdx.x; int b = bj / J, j = bj % J;
  int t = threadIdx.x;
  float x0 = x_t[(b*J+j)*3+0];
  float x1 = x_t[(b*J+j)*3+1];
  float x2 = x_t[(b*J+j)*3+2];
  float sx = x0*x0+x1*x1+x2*x2;
  float ar = c_scale[j]*0.1f;
  float sig = ar*0.5f;
  float twos2 = 2.f*sig*sig;
  float sum = 0.f, bmin = 3.4e38f; int bidx = NP; int any = 0;
  for (int n = t; n < NP; n += 256){
    const float* p = pc + ((size_t)b*NP + n)*6;
    float p0=p[0], p1=p[1], p2=p[2];
    float d2 = sx + (p0*p0+p1*p1+p2*p2) - 2.f*(x0*p0+x1*p1+x2*p2);
    float dist = sqrtf(fmaxf(d2, 0.f));
    sum += expf(-(dist*dist)/twos2);
    if (dist < bmin){ bmin = dist; bidx = n; }
    if (dist <= ar){ any = 1; atomicOr(&bitmap[b*(NP/32)+(n>>5)], 1u<<(n&31)); }
  }
  __shared__ float ssum[256]; __shared__ float smin[256];
  __shared__ int sidx[256]; __shared__ int sany[256];
  ssum[t]=sum; smin[t]=bmin; sidx[t]=bidx; sany[t]=any;
  __syncthreads();
  for (int s = 128; s > 0; s >>= 1){
    if (t < s){
      ssum[t] += ssum[t+s];
      if (smin[t+s] < smin[t] || (smin[t+s]==smin[t] && sidx[t+s] < sidx[t])){ smin[t]=smin[t+s]; sidx[t]=sidx[t+s]; }
      sany[t] |= sany[t+s];
    }
    __syncthreads();
  }
  if (t == 0){
    denom_sum[bj] = ssum[0];
    rescue[bj] = sidx[0];
    allm[bj] = sany[0] ? 0 : 1;
    if (!sany[0]) atomicOr(&bitmap[b*(NP/32)+(sidx[0]>>5)], 1u<<(sidx[0]&31));
  }
}

// ---------- ordered compaction of active bitmap -> per-batch index list (1 wave / batch) ----------
__global__ void k_compact(const unsigned int* __restrict__ bitmap, int* __restrict__ act_idx,
                          int* __restrict__ act_cnt){
  int b = blockIdx.x; int t = threadIdx.x; // 64 threads = 1 wave
  unsigned int w = bitmap[b*(NP/32)+t];
  int c = __popc(w);
  int off = c;
  for (int s = 1; s < 64; s <<= 1){
    int v = __shfl_up(off, s);
    if (t >= s) off += v;
  }
  int total = __shfl(off, 63);
  off -= c; // exclusive
  int base = off;
  for (int bit = 0; bit < 32; ++bit){
    if (w & (1u<<bit)){
      if (base < CAP) act_idx[b*CAP+base] = t*32+bit;
      base++;
    }
  }
  if (t == 0) act_cnt[b] = total > CAP ? CAP : total;
}

__global__ void k_scan(const int* __restrict__ act_cnt, int* __restrict__ act_off,
                       int* __restrict__ act_total){
  if (threadIdx.x == 0){
    int s = 0;
    for (int b = 0; b < NB; ++b){ act_off[b] = s; s += act_cnt[b]; }
    act_total[0] = s;
  }
}

// ---------- G[b,ch,j,h] = sum_n dw[b,j,n] * silu(dop*w1[h]+b1[h])  (fully parallel chunks) ----------
__launch_bounds__(256)
__global__ void k_gpart(const float* __restrict__ x_t, const float* __restrict__ pc,
                        const float* __restrict__ dop_w1, const float* __restrict__ dop_b1,
                        float* __restrict__ Gp){
  int b = blockIdx.x, ch = blockIdx.y; int t = threadIdx.x;
  __shared__ float sx[J*3];
  __shared__ float w1s[64], b1s[64];
  __shared__ float spx[GPTS], spy[GPTS], spz[GPTS], sdp[GPTS];
  __shared__ float hid[GPTS*65];
  __shared__ float dws[J*129];
  if (t < J*3) sx[t] = x_t[b*J*3 + t];
  if (t < 64){ w1s[t] = dop_w1[t]; b1s[t] = dop_b1[t]; }
  int n0 = ch*GPTS;
  if (t < GPTS){
    const float* p = pc + ((size_t)b*NP + n0 + t)*6;
    float2 f0 = *(const float2*)p;
    float2 f1 = *(const float2*)(p+2);
    spx[t]=f0.x; spy[t]=f0.y; spz[t]=f1.x; sdp[t]=f1.y;
  }
  __syncthreads();
  { // hid: 2 threads per point, 32 h each
    int p = t>>1, h0 = (t&1)*32;
    float dop = sdp[p];
    #pragma unroll 8
    for (int i = 0; i < 32; ++i){
      int h = h0 + i;
      hid[p*65+h] = siluf(dop*w1s[h]+b1s[h]);
    }
  }
  for (int e = t; e < J*GPTS; e += 256){
    int j = e>>7, p = e&127;
    float x0=sx[j*3], x1=sx[j*3+1], x2=sx[j*3+2];
    float p0=spx[p], p1=spy[p], p2=spz[p];
    float d2 = (x0*x0+x1*x1+x2*x2) + (p0*p0+p1*p1+p2*p2) - 2.f*(x0*p0+x1*p1+x2*p2);
    float dist = sqrtf(fmaxf(d2, 0.f));
    float sig = c_scale[j]*0.05f;
    dws[j*129+p] = expf(-(dist*dist)/(2.f*sig*sig));
  }
  __syncthreads();
  // G[j][h] = sum_p dws[j][p]*hid[p][h]; thread: h = t&63, j in {jb, jb+4, ...}
  int h = t & 63, jb = t >> 6;
  float acc[7] = {0.f,0.f,0.f,0.f,0.f,0.f,0.f};
  for (int p = 0; p < GPTS; ++p){
    float hv = hid[p*65+h];
    #pragma unroll
    for (int i = 0; i < 7; ++i){
      int j = jb + 4*i;
      if (j < J) acc[i] += dws[j*129+p]*hv;
    }
  }
  float* out = Gp + ((size_t)(b*GCH+ch))*J*64;
  #pragma unroll
  for (int i = 0; i < 7; ++i){
    int j = jb + 4*i;
    if (j < J) out[j*64+h] = acc[i];
  }
}

// ---------- h_dop[b,j,:] = (G @ w2 + S*b2) / (S + 1e-6) ----------
__global__ void k_hdop2(const float* __restrict__ Gp, const float* __restrict__ dop_w2,
                        const float* __restrict__ dop_b2, const float* __restrict__ denom_sum,
                        float* __restrict__ h_dop){
  int bj = blockIdx.x; int b = bj/J, j = bj%J; int t = threadIdx.x; // 64
  __shared__ float G[64];
  float g = 0.f;
  for (int c = 0; c < GCH; ++c) g += Gp[((size_t)(b*GCH+c)*J + j)*64 + t];
  G[t] = g; __syncthreads();
  float S = denom_sum[bj];
  float inv = 1.f/(S + 1e-6f);
  float* out = h_dop + (size_t)bj*D;
  for (int u = 0; u < D/64; ++u){
    int d = u*64 + t;
    float acc = 0.f;
    for (int hh = 0; hh < 64; ++hh) acc += G[hh]*dop_w2[hh*D+d];
    out[d] = (acc + S*dop_b2[d]) * inv;
  }
}

// ---------- out[r,d] = in[r,0..2] @ w(3,D) + b ----------
__global__ void k_proj3(const float* __restrict__ in, const float* __restrict__ w,
                        const float* __restrict__ bias, float* __restrict__ out, int M){
  int idx = blockIdx.x*256 + threadIdx.x;
  if (idx >= M*D) return;
  int r = idx / D, d = idx % D;
  const float* ir = in + r*3;
  out[idx] = ir[0]*w[d] + ir[1]*w[D+d] + ir[2]*w[2*D+d] + bias[d];
}

__global__ void k_th(const float* __restrict__ t_in, const float* __restrict__ w1,
                     const float* __restrict__ b1, float* __restrict__ th){
  int idx = blockIdx.x*256 + threadIdx.x;
  if (idx >= NB*D) return;
  int b = idx / D, d = idx % D;
  th[idx] = siluf(t_in[b]*w1[d] + b1[d]);
}

__global__ void k_hs2(const float* __restrict__ h_state, float* __restrict__ hs2){
  int idx = blockIdx.x*256 + threadIdx.x;
  if (idx >= NB*J*2*D) return;
  int r = idx / (2*D), c = idx % (2*D);
  int b = r / J, j = r % J;
  float v;
  if (c < D) v = h_state[(size_t)r*D + c];
  else       v = h_state[((size_t)(b*J) + c_parent[j])*D + (c-D)];
  hs2[idx] = v;
}

__global__ void k_query(const float* __restrict__ h_coarse, const float* __restrict__ h_time,
                        const float* __restrict__ h_dop, const float* __restrict__ h_state,
                        const float* __restrict__ hstruct, const float* __restrict__ jid,
                        const float* __restrict__ mod2, float* __restrict__ x){
  int idx = blockIdx.x*256 + threadIdx.x;
  if (idx >= NB*J*D) return;
  int r = idx / D, d = idx % D;
  int b = r / J, j = r % J;
  float q = h_coarse[idx] + h_time[b*D+d] + h_dop[idx] + h_state[idx] + hstruct[idx] + jid[j*D+d];
  float shift = mod2[(size_t)r*2*D + d];
  float scale = mod2[(size_t)r*2*D + D + d];
  x[idx] = q*(1.f+scale) + shift;
}

// ---------- memory rows for active points only (compacted) ----------
__global__ void k_memact(const float* __restrict__ x_t, const float* __restrict__ pc,
                         const float* __restrict__ pc_w, const float* __restrict__ pc_b,
                         const int* __restrict__ act_idx, const int* __restrict__ act_cnt,
                         const int* __restrict__ act_off, float* __restrict__ mem_act){
  int b = blockIdx.x / CAP, i = blockIdx.x % CAP;
  if (i >= act_cnt[b]) return;
  int n = act_idx[b*CAP+i];
  int t = threadIdx.x; // 128
  __shared__ float sdw[J];
  __shared__ float spi;
  const float* p = pc + ((size_t)b*NP+n)*6;
  if (t < J){
    float x0 = x_t[(b*J+t)*3+0], x1 = x_t[(b*J+t)*3+1], x2 = x_t[(b*J+t)*3+2];
    float p0=p[0], p1=p[1], p2=p[2];
    float d2 = (x0*x0+x1*x1+x2*x2) + (p0*p0+p1*p1+p2*p2) - 2.f*(x0*p0+x1*p1+x2*p2);
    float dist = sqrtf(fmaxf(d2,0.f));
    float sig = c_scale[t]*0.05f;
    sdw[t] = expf(-(dist*dist)/(2.f*sig*sig));
  }
  __syncthreads();
  if (t == 0){ float m = sdw[0]; for (int k = 1; k < J; ++k) m = fmaxf(m, sdw[k]); spi = m; }
  __syncthreads();
  float pi = spi;
  float p0=p[0],p1=p[1],p2=p[2],p3=p[3],p4=p[4],p5=p[5];
  int g = act_off[b] + i;
  float* out = mem_act + (size_t)g*D;
  for (int d = t; d < D; d += 128){
    float acc = pc_b[d] + p0*pc_w[d] + p1*pc_w[D+d] + p2*pc_w[2*D+d]
              + p3*pc_w[3*D+d] + p4*pc_w[4*D+d] + p5*pc_w[5*D+d];
    out[d] = acc * pi;
  }
}

// ---------- MFMA bf16 hi/lo split GEMM: C = act(A@W + bias [+ res]) ----------
// 128x128 tile, BK=32, 4 waves (2x2), each wave 64x64 = 4x4 frags of 16x16x32.
// Register-prefetch pipeline; M-major grid with bijective XCD chunking.
#define GST 40  // bf16 elems per LDS row (32 + 8 pad) -> 80B rows, 16B-aligned frags
__launch_bounds__(256)
__global__ void k_gemm(const float* __restrict__ A, int lda,
                       const float* __restrict__ W, int ldw,
                       const float* __restrict__ bias,
                       const float* __restrict__ res,
                       float* __restrict__ C, int ldc,
                       int M, int N, int K, int act, const int* __restrict__ Mdev,
                       int ntx){
  int Meff = Mdev ? *Mdev : M;
  // bijective XCD chunk swizzle (m204), M-major tile order
  int nwg = gridDim.x;
  int q = nwg >> 3, r8 = nwg & 7;
  int xcd = blockIdx.x & 7, local = blockIdx.x >> 3;
  int wg = (xcd < r8 ? xcd*(q+1) : r8*(q+1) + (xcd - r8)*q) + local;
  int row0 = (wg % ntx) * 128, col0 = (wg / ntx) * 128;
  if (row0 >= Meff) return;

  __shared__ unsigned short Ah[128*GST], Al[128*GST];
  __shared__ unsigned short Bh[128*GST], Bl[128*GST];
  int t = threadIdx.x;
  int lane = t & 63, w = t >> 6;
  int wr = w >> 1, wc = w & 1;          // wave 2x2 -> 64x64 each
  int arow = t >> 1, akq = (t & 1) * 16;     // A staging: 16 floats/thread
  int bcol = t & 127, bkq = (t >> 7) * 16;   // B staging: 16 strided floats/thread
  int fr = lane & 15;
  int fk = (lane >> 4) * 8;
  f32x4 acc[4][4] = {};
  float va[16], vb[16];

  auto loadA = [&](int kt){
    int r = row0 + arow;
    if (r < Meff){
      const float* ap = A + (size_t)r*lda + kt + akq;
      float4 v0 = *(const float4*)(ap+0);
      float4 v1 = *(const float4*)(ap+4);
      float4 v2 = *(const float4*)(ap+8);
      float4 v3 = *(const float4*)(ap+12);
      va[0]=v0.x; va[1]=v0.y; va[2]=v0.z; va[3]=v0.w;
      va[4]=v1.x; va[5]=v1.y; va[6]=v1.z; va[7]=v1.w;
      va[8]=v2.x; va[9]=v2.y; va[10]=v2.z; va[11]=v2.w;
      va[12]=v3.x; va[13]=v3.y; va[14]=v3.z; va[15]=v3.w;
    } else {
      #pragma unroll
      for (int i = 0; i < 16; ++i) va[i] = 0.f;
    }
  };
  auto loadB = [&](int kt){
    const float* wp = W + (size_t)(kt + bkq)*ldw + col0 + bcol;
    #pragma unroll
    for (int i = 0; i < 16; ++i) vb[i] = wp[(size_t)i*ldw];
  };
  auto stage = [&](){
    unsigned h[8], l[8];
    #pragma unroll
    for (int i = 0; i < 8; ++i) split2(va[2*i], va[2*i+1], h[i], l[i]);
    int o = arow*GST + akq;
    *(uint4*)&Ah[o]   = make_uint4(h[0],h[1],h[2],h[3]);
    *(uint4*)&Ah[o+8] = make_uint4(h[4],h[5],h[6],h[7]);
    *(uint4*)&Al[o]   = make_uint4(l[0],l[1],l[2],l[3]);
    *(uint4*)&Al[o+8] = make_uint4(l[4],l[5],l[6],l[7]);
    #pragma unroll
    for (int i = 0; i < 8; ++i) split2(vb[2*i], vb[2*i+1], h[i], l[i]);
    o = bcol*GST + bkq;
    *(uint4*)&Bh[o]   = make_uint4(h[0],h[1],h[2],h[3]);
    *(uint4*)&Bh[o+8] = make_uint4(h[4],h[5],h[6],h[7]);
    *(uint4*)&Bl[o]   = make_uint4(l[0],l[1],l[2],l[3]);
    *(uint4*)&Bl[o+8] = make_uint4(l[4],l[5],l[6],l[7]);
  };

  loadA(0); loadB(0);
  stage();
  __syncthreads();

  for (int kt = 0; kt < K; kt += 32){
    bool hn = (kt + 32) < K;
    if (hn){ loadA(kt+32); loadB(kt+32); }  // prefetch: latency hides under ds_read+MFMA
    bf16x8 ah[4], al[4], bh[4], bl[4];
    #pragma unroll
    for (int m = 0; m < 4; ++m){
      int o = (wr*64 + m*16 + fr)*GST + fk;
      ah[m] = *(const bf16x8*)&Ah[o];
      al[m] = *(const bf16x8*)&Al[o];
    }
    #pragma unroll
    for (int n = 0; n < 4; ++n){
      int o = (wc*64 + n*16 + fr)*GST + fk;
      bh[n] = *(const bf16x8*)&Bh[o];
      bl[n] = *(const bf16x8*)&Bl[o];
    }
    #pragma unroll
    for (int m = 0; m < 4; ++m)
      #pragma unroll
      for (int n = 0; n < 4; ++n){
        acc[m][n] = __builtin_amdgcn_mfma_f32_16x16x32_bf16(al[m], bh[n], acc[m][n], 0, 0, 0);
        acc[m][n] = __builtin_amdgcn_mfma_f32_16x16x32_bf16(ah[m], bl[n], acc[m][n], 0, 0, 0);
        acc[m][n] = __builtin_amdgcn_mfma_f32_16x16x32_bf16(ah[m], bh[n], acc[m][n], 0, 0, 0);
      }
    if (hn){
      __syncthreads();
      stage();
      __syncthreads();
    }
  }

  // epilogue: C/D layout col=lane&15, row=(lane>>4)*4+q
  int er = (lane >> 4) * 4, ec = lane & 15;
  #pragma unroll
  for (int m = 0; m < 4; ++m){
    #pragma unroll
    for (int qq = 0; qq < 4; ++qq){
      int r = row0 + wr*64 + m*16 + er + qq;
      if (r >= Meff) continue;
      #pragma unroll
      for (int n = 0; n < 4; ++n){
        int c = col0 + wc*64 + n*16 + ec;
        float v = acc[m][n][qq] + bias[c];
        if (res) v += res[(size_t)r*ldc + c];
        if (act == 1) v = v/(1.f+expf(-v));
        else if (act == 2) v = fmaxf(v, 0.f);
        C[(size_t)r*ldc + c] = v;
      }
    }
  }
}

// ---------- LayerNorm over D, per row ----------
__global__ void k_ln(const float* __restrict__ x, const float* __restrict__ s,
                     const float* __restrict__ bb, float* __restrict__ out){
  int r = blockIdx.x; int t = threadIdx.x; // 256
  const float* xr = x + (size_t)r*D;
  float v0 = xr[t], v1 = xr[t+256];
  __shared__ float red[256];
  red[t] = v0+v1; __syncthreads();
  for (int st = 128; st > 0; st >>= 1){ if (t < st) red[t] += red[t+st]; __syncthreads(); }
  float mu = red[0]/(float)D;
  __syncthreads();
  float d0 = v0-mu, d1 = v1-mu;
  red[t] = d0*d0 + d1*d1; __syncthreads();
  for (int st = 128; st > 0; st >>= 1){ if (t < st) red[t] += red[t+st]; __syncthreads(); }
  float var = red[0]/(float)D;
  float rs = rsqrtf(var + 1e-5f);
  out[(size_t)r*D + t]       = d0*rs*s[t]       + bb[t];
  out[(size_t)r*D + t + 256] = d1*rs*s[t+256]   + bb[t+256];
}

// ---------- self-attn: one (b,h) per block, J=27 tokens, topo mask ----------
__launch_bounds__(256)
__global__ void k_selfattn(const float* __restrict__ qkv, float* __restrict__ attno){
  int bh = blockIdx.x; int b = bh / H, h = bh % H;
  int t = threadIdx.x;
  __shared__ float qs[J*DH], ks[J*DH], vs[J*DH];
  __shared__ float ss[J*J];
  for (int e = t; e < J*DH; e += 256){
    int j = e/DH, d = e%DH;
    const float* base = qkv + (size_t)(b*J+j)*1536 + h*DH + d;
    qs[e] = base[0]; ks[e] = base[512]; vs[e] = base[1024];
  }
  __syncthreads();
  for (int e = t; e < J*J; e += 256){
    int qj = e/J, kk = e%J;
    float acc = 0.f;
    for (int d = 0; d < DH; ++d) acc += qs[qj*DH+d]*ks[kk*DH+d];
    float bias = (qj==kk || c_parent[qj]==kk || c_parent[kk]==qj) ? 0.f : NEGF;
    ss[e] = acc*0.125f + bias;
  }
  __syncthreads();
  if (t < J){
    float m = -3.4e38f;
    for (int k = 0; k < J; ++k) m = fmaxf(m, ss[t*J+k]);
    float sum = 0.f;
    for (int k = 0; k < J; ++k){ float e_ = expf(ss[t*J+k]-m); ss[t*J+k] = e_; sum += e_; }
    float inv = 1.f/sum;
    for (int k = 0; k < J; ++k) ss[t*J+k] *= inv;
  }
  __syncthreads();
  for (int e = t; e < J*DH; e += 256){
    int j = e/DH, d = e%DH;
    float acc = 0.f;
    for (int k = 0; k < J; ++k) acc += ss[j*J+k]*vs[k*DH+d];
    attno[(size_t)(b*J+j)*D + h*DH + d] = acc;
  }
}

// ---------- cross-attn over active points only ----------
__launch_bounds__(256)
__global__ void k_crossattn(const float* __restrict__ qbuf, const float* __restrict__ kv_act,
                            const float* __restrict__ x_t, const float* __restrict__ pc,
                            const int* __restrict__ act_idx, const int* __restrict__ act_cnt,
                            const int* __restrict__ act_off, const int* __restrict__ rescue,
                            const int* __restrict__ allm, float* __restrict__ attno){
  int bh = blockIdx.x; int b = bh / H, h = bh % H;
  int t = threadIdx.x;
  int cnt = act_cnt[b], off = act_off[b];
  __shared__ float qs[J*DH];
  __shared__ float ks[CAP*DH];
  __shared__ float pxyz[CAP*3];
  __shared__ float sx[J*3];
  __shared__ int sn[CAP];
  __shared__ float ss[J*CAP];
  if (t < J*3) sx[t] = x_t[b*J*3+t];
  for (int e = t; e < J*DH; e += 256)
    qs[e] = qbuf[(size_t)(b*J + e/DH)*D + h*DH + (e%DH)];
  for (int e = t; e < cnt*DH; e += 256){
    int i = e/DH, d = e%DH;
    ks[e] = kv_act[(size_t)(off+i)*1024 + h*DH + d];
  }
  for (int i = t; i < cnt; i += 256){
    int n = act_idx[b*CAP+i]; sn[i] = n;
    const float* p = pc + ((size_t)b*NP+n)*6;
    pxyz[i*3] = p[0]; pxyz[i*3+1] = p[1]; pxyz[i*3+2] = p[2];
  }
  __syncthreads();
  for (int e = t; e < J*cnt; e += 256){
    int j = e/cnt, i = e%cnt;
    float acc = 0.f;
    for (int d = 0; d < DH; ++d) acc += qs[j*DH+d]*ks[i*DH+d];
    float bias;
    if (allm[b*J+j]) bias = (sn[i] == rescue[b*J+j]) ? 0.f : NEGF;
    else {
      float x0=sx[j*3], x1=sx[j*3+1], x2=sx[j*3+2];
      float p0=pxyz[i*3], p1=pxyz[i*3+1], p2=pxyz[i*3+2];
      float d2 = (x0*x0+x1*x1+x2*x2) + (p0*p0+p1*p1+p2*p2) - 2.f*(x0*p0+x1*p1+x2*p2);
      float dist = sqrtf(fmaxf(d2,0.f));
      float ar = c_scale[j]*0.1f;
      bias = (dist > ar) ? NEGF : 0.f;
    }
    ss[j*CAP+i] = acc*0.125f + bias;
  }
  __syncthreads();
  if (t < J){
    float m = -3.4e38f;
    for (int i = 0; i < cnt; ++i) m = fmaxf(m, ss[t*CAP+i]);
    float sum = 0.f;
    for (int i = 0; i < cnt; ++i){ float e_ = expf(ss[t*CAP+i]-m); ss[t*CAP+i] = e_; sum += e_; }
    float inv = 1.f/sum;
    for (int i = 0; i < cnt; ++i) ss[t*CAP+i] *= inv;
  }
  __syncthreads();
  for (int e = t; e < J*DH; e += 256){
    int j = e/DH, d = e%DH;
    float acc = 0.f;
    for (int i = 0; i < cnt; ++i)
      acc += ss[j*CAP+i]*kv_act[(size_t)(off+i)*1024 + 512 + h*DH + d];
    attno[(size_t)(b*J+j)*D + h*DH + d] = acc;
  }
}

// ---------- final vel projection (D -> 3) ----------
__global__ void k_vel(const float* __restrict__ x, const float* __restrict__ vel_w,
                      const float* __restrict__ vel_b, float* __restrict__ out){
  int r = blockIdx.x; int t = threadIdx.x; // 192 = 3 waves
  int c = t >> 6; int lane = t & 63;
  float acc = 0.f;
  const float* xr = x + (size_t)r*D;
  for (int d = lane; d < D; d += 64) acc += xr[d]*vel_w[d*3+c];
  for (int s = 32; s > 0; s >>= 1) acc += __shfl_down(acc, s);
  if (lane == 0) out[r*3+c] = acc + vel_b[c];
}

// ============================================================================
static void gemm(const float* A, int lda, const float* W, int ldw, const float* bias,
                 const float* res, float* C, int ldc, int M, int N, int K, int act,
                 const int* Mdev, hipStream_t s){
  int ntx = (M + 127) / 128, nty = N / 128;
  k_gemm<<<ntx*nty, 256, 0, s>>>(A, lda, W, ldw, bias, res, C, ldc, M, N, K, act, Mdev, ntx);
}

extern "C" void kernel_launch(void* const* d_in, const int* in_sizes, int n_in,
                              void* d_out, int out_size, void* d_ws, size_t ws_size,
                              hipStream_t stream){
  const float* x_t        = (const float*)d_in[0];
  const float* t_in       = (const float*)d_in[1];
  const float* coarse     = (const float*)d_in[2];
  const float* radar      = (const float*)d_in[3];
  const float* pc_w       = (const float*)d_in[4];
  const float* pc_b       = (const float*)d_in[5];
  const float* coarse_w   = (const float*)d_in[6];
  const float* coarse_b   = (const float*)d_in[7];
  const float* state_w    = (const float*)d_in[8];
  const float* state_b    = (const float*)d_in[9];
  const float* jid_emb    = (const float*)d_in[10];
  const float* dop_w1     = (const float*)d_in[11];
  const float* dop_b1     = (const float*)d_in[12];
  const float* dop_w2     = (const float*)d_in[13];
  const float* dop_b2     = (const float*)d_in[14];
  const float* time_w1    = (const float*)d_in[15];
  const float* time_b1    = (const float*)d_in[16];
  const float* time_w2    = (const float*)d_in[17];
  const float* time_b2    = (const float*)d_in[18];
  const float* mod_w1     = (const float*)d_in[19];
  const float* mod_b1     = (const float*)d_in[20];
  const float* mod_w2     = (const float*)d_in[21];
  const float* mod_b2     = (const float*)d_in[22];
  const float* diff_w     = (const float*)d_in[23];
  const float* diff_b     = (const float*)d_in[24];
  const float* vel_w      = (const float*)d_in[25];
  const float* vel_b      = (const float*)d_in[26];
  const float* sa_qkv_w   = (const float*)d_in[27];
  const float* sa_qkv_b   = (const float*)d_in[28];
  const float* sa_out_w   = (const float*)d_in[29];
  const float* sa_out_b   = (const float*)d_in[30];
  const float* ca_qkv_w   = (const float*)d_in[31];
  const float* ca_qkv_b   = (const float*)d_in[32];
  const float* ca_out_w   = (const float*)d_in[33];
  const float* ca_out_b   = (const float*)d_in[34];
  const float* ff1_w      = (const float*)d_in[35];
  const float* ff1_b      = (const float*)d_in[36];
  const float* ff2_w      = (const float*)d_in[37];
  const float* ff2_b      = (const float*)d_in[38];
  const float* ln1_s      = (const float*)d_in[39];
  const float* ln1_b      = (const float*)d_in[40];
  const float* ln2_s      = (const float*)d_in[41];
  const float* ln2_b      = (const float*)d_in[42];
  const float* ln3_s      = (const float*)d_in[43];
  const float* ln3_b      = (const float*)d_in[44];
  (void)in_sizes; (void)n_in; (void)out_size; (void)ws_size;

  const int R = NB*J; // 1728 rows

  // bump allocator over d_ws (256B aligned)
  char* wp = (char*)d_ws;
  auto alloc = [&](size_t bytes)->void*{
    void* r = (void*)wp;
    wp += (bytes + 255) & ~(size_t)255;
    return r;
  };
  float*        denom_sum = (float*)alloc(R*4);
  int*          rescue    = (int*)  alloc(R*4);
  int*          allm      = (int*)  alloc(R*4);
  unsigned int* bitmap    = (unsigned int*)alloc(NB*(NP/32)*4);
  int*          act_idx   = (int*)  alloc(NB*CAP*4);
  int*          act_cnt   = (int*)  alloc(NB*4);
  int*          act_off   = (int*)  alloc(NB*4);
  int*          act_total = (int*)  alloc(64);
  float* Gp       = (float*)alloc((size_t)NB*GCH*J*64*4);
  float* h_dop    = (float*)alloc((size_t)R*D*4);
  float* h_state  = (float*)alloc((size_t)R*D*4);
  float* h_coarse = (float*)alloc((size_t)R*D*4);
  float* hstruct  = (float*)alloc((size_t)R*D*4);
  float* xres     = (float*)alloc((size_t)R*D*4);
  float* hbuf     = (float*)alloc((size_t)R*D*4);
  float* attno    = (float*)alloc((size_t)R*D*4);
  float* qbuf     = (float*)alloc((size_t)R*D*4);
  float* th       = (float*)alloc((size_t)NB*D*4);
  float* h_time   = (float*)alloc((size_t)NB*D*4);
  float* mod1     = (float*)alloc((size_t)R*2*D*4);   // ffh aliases mod1+mod2
  float* mod2     = (float*)alloc((size_t)R*2*D*4);
  float* qkv      = (float*)alloc((size_t)R*3*D*4);   // hs2 aliases qkv
  float* mem_act  = (float*)alloc((size_t)NB*CAP*D*4);
  float* kv_act   = (float*)alloc((size_t)NB*CAP*2*D*4);
  float* ffh = mod1;       // (R,2048) = mod1(R,1024)+mod2(R,1024) contiguous
  float* hs2 = qkv;        // (R,1024) fits in qkv (R,1536)

  // ---- stage 0: masks / active set / h_dop ----
  hipMemsetAsync(bitmap, 0, NB*(NP/32)*4, stream);
  k_perj<<<R, 256, 0, stream>>>(x_t, radar, denom_sum, rescue, allm, bitmap);
  k_compact<<<NB, 64, 0, stream>>>(bitmap, act_idx, act_cnt);
  k_scan<<<1, 64, 0, stream>>>(act_cnt, act_off, act_total);
  k_gpart<<<dim3(NB, GCH), 256, 0, stream>>>(x_t, radar, dop_w1, dop_b1, Gp);
  k_hdop2<<<R, 64, 0, stream>>>(Gp, dop_w2, dop_b2, denom_sum, h_dop);

  // ---- stage 1: query build ----
  k_proj3<<<(R*D+255)/256, 256, 0, stream>>>(x_t, state_w, state_b, h_state, R);
  k_proj3<<<(R*D+255)/256, 256, 0, stream>>>(coarse, coarse_w, coarse_b, h_coarse, R);
  k_th<<<(NB*D+255)/256, 256, 0, stream>>>(t_in, time_w1, time_b1, th);
  gemm(th, D, time_w2, D, time_b2, nullptr, h_time, D, NB, D, D, 0, nullptr, stream);
  gemm(h_state, D, mod_w1, 2*D, mod_b1, nullptr, mod1, 2*D, R, 2*D, D, 1, nullptr, stream);
  gemm(mod1, 2*D, mod_w2, 2*D, mod_b2, nullptr, mod2, 2*D, R, 2*D, 2*D, 0, nullptr, stream);
  k_hs2<<<(R*2*D+255)/256, 256, 0, stream>>>(h_state, hs2);
  gemm(hs2, 2*D, diff_w, D, diff_b, nullptr, hstruct, D, R, D, 2*D, 0, nullptr, stream);
  k_query<<<(R*D+255)/256, 256, 0, stream>>>(h_coarse, h_time, h_dop, h_state, hstruct,
                                             jid_emb, mod2, xres);
  k_memact<<<NB*CAP, 128, 0, stream>>>(x_t, radar, pc_w, pc_b, act_idx, act_cnt, act_off, mem_act);

  // ---- stage 2: transformer layers ----
  for (int l = 0; l < NLAYER; ++l){
    k_ln<<<R, 256, 0, stream>>>(xres, ln1_s + l*D, ln1_b + l*D, hbuf);
    gemm(hbuf, D, sa_qkv_w + (size_t)l*D*3*D, 3*D, sa_qkv_b + l*3*D, nullptr,
         qkv, 3*D, R, 3*D, D, 0, nullptr, stream);
    k_selfattn<<<NB*H, 256, 0, stream>>>(qkv, attno);
    gemm(attno, D, sa_out_w + (size_t)l*D*D, D, sa_out_b + l*D, xres,
         xres, D, R, D, D, 0, nullptr, stream);

    k_ln<<<R, 256, 0, stream>>>(xres, ln2_s + l*D, ln2_b + l*D, hbuf);
    gemm(hbuf, D, ca_qkv_w + (size_t)l*D*3*D, 3*D, ca_qkv_b + l*3*D, nullptr,
         qbuf, D, R, D, D, 0, nullptr, stream);
    gemm(mem_act, D, ca_qkv_w + (size_t)l*D*3*D + D, 3*D, ca_qkv_b + l*3*D + D, nullptr,
         kv_act, 2*D, NB*CAP, 2*D, D, 0, act_total, stream);
    k_crossattn<<<NB*H, 256, 0, stream>>>(qbuf, kv_act, x_t, radar, act_idx, act_cnt,
                                          act_off, rescue, allm, attno);
    gemm(attno, D, ca_out_w + (size_t)l*D*D, D, ca_out_b + l*D, xres,
         xres, D, R, D, D, 0, nullptr, stream);

    k_ln<<<R, 256, 0, stream>>>(xres, ln3_s + l*D, ln3_b + l*D, hbuf);
    gemm(hbuf, D, ff1_w + (size_t)l*D*DFF, DFF, ff1_b + l*DFF, nullptr,
         ffh, DFF, R, DFF, D, 2, nullptr, stream);
    gemm(ffh, DFF, ff2_w + (size_t)l*DFF*D, D, ff2_b + l*D, xres,
         xres, D, R, D, DFF, 0, nullptr, stream);
  }

  k_vel<<<R, 192, 0, stream>>>(xres, vel_w, vel_b, (float*)d_out);
}

// Round 4
// 1383.937 us; speedup vs baseline: 2.3489x; 2.3489x over previous
//
#include <hip/hip_runtime.h>

#define J 27
#define D 512
#define H 8
#define DH 64
#define NLAYER 6
#define DFF 2048
#define NB 64
#define NP 2048
#define CAP 128
#define GCH 16
#define GPTS 128
#define NEGF -1000000000.0f

typedef unsigned short u16;
typedef __attribute__((ext_vector_type(8))) __bf16 bf16x8;
typedef __attribute__((ext_vector_type(4))) float f32x4;

__constant__ int c_parent[J] = {0,0,1,2,3,4,5,6,7,8,8,3,11,12,13,14,15,15,0,18,19,20,0,22,23,24,3};
__constant__ float c_scale[J] = {0.6f,0.6f,0.6f,0.6f,1.f,1.f,1.f,1.f,1.f,1.5f,1.5f,1.f,1.f,1.f,1.f,1.f,
                                 1.5f,1.5f,0.6f,1.f,1.5f,1.5f,0.6f,1.f,1.5f,1.5f,1.5f};

__device__ __forceinline__ float siluf(float x){ return x/(1.f+expf(-x)); }

// round-to-nearest-even fp32 -> bf16
__device__ __forceinline__ u16 f2bf(float f){
  union { float f; unsigned u; } x; x.f = f;
  unsigned r = x.u + 0x7FFFu + ((x.u >> 16) & 1u);
  return (u16)(r >> 16);
}
__device__ __forceinline__ float bf2f(u16 h){
  union { unsigned u; float f; } x; x.u = ((unsigned)h) << 16; return x.f;
}
// hi = rn(v), lo = rn(v - hi): hi+lo carries ~2^-17 relative error
__device__ __forceinline__ void csplit(float v, u16 &h, u16 &l){
  h = f2bf(v);
  l = f2bf(v - bf2f(h));
}

// ---------- per (b,j): denom sum, rescue idx, allmask, active-bitmap marks ----------
__global__ void k_perj(const float* __restrict__ x_t, const float* __restrict__ pc,
                       float* __restrict__ denom_sum, int* __restrict__ rescue,
                       int* __restrict__ allm, unsigned int* __restrict__ bitmap){
  int bj = blockIdx.x; int b = bj / J, j = bj % J;
  int t = threadIdx.x;
  float x0 = x_t[(b*J+j)*3+0];
  float x1 = x_t[(b*J+j)*3+1];
  float x2 = x_t[(b*J+j)*3+2];
  float sx = x0*x0+x1*x1+x2*x2;
  float ar = c_scale[j]*0.1f;
  float sig = ar*0.5f;
  float twos2 = 2.f*sig*sig;
  float sum = 0.f, bmin = 3.4e38f; int bidx = NP; int any = 0;
  for (int n = t; n < NP; n += 256){
    const float* p = pc + ((size_t)b*NP + n)*6;
    float p0=p[0], p1=p[1], p2=p[2];
    float d2 = sx + (p0*p0+p1*p1+p2*p2) - 2.f*(x0*p0+x1*p1+x2*p2);
    float dist = sqrtf(fmaxf(d2, 0.f));
    sum += expf(-(dist*dist)/twos2);
    if (dist < bmin){ bmin = dist; bidx = n; }
    if (dist <= ar){ any = 1; atomicOr(&bitmap[b*(NP/32)+(n>>5)], 1u<<(n&31)); }
  }
  __shared__ float ssum[256]; __shared__ float smin[256];
  __shared__ int sidx[256]; __shared__ int sany[256];
  ssum[t]=sum; smin[t]=bmin; sidx[t]=bidx; sany[t]=any;
  __syncthreads();
  for (int s = 128; s > 0; s >>= 1){
    if (t < s){
      ssum[t] += ssum[t+s];
      if (smin[t+s] < smin[t] || (smin[t+s]==smin[t] && sidx[t+s] < sidx[t])){ smin[t]=smin[t+s]; sidx[t]=sidx[t+s]; }
      sany[t] |= sany[t+s];
    }
    __syncthreads();
  }
  if (t == 0){
    denom_sum[bj] = ssum[0];
    rescue[bj] = sidx[0];
    allm[bj] = sany[0] ? 0 : 1;
    if (!sany[0]) atomicOr(&bitmap[b*(NP/32)+(sidx[0]>>5)], 1u<<(sidx[0]&31));
  }
}

// ---------- ordered compaction of active bitmap ----------
__global__ void k_compact(const unsigned int* __restrict__ bitmap, int* __restrict__ act_idx,
                          int* __restrict__ act_cnt){
  int b = blockIdx.x; int t = threadIdx.x; // 64 = 1 wave
  unsigned int w = bitmap[b*(NP/32)+t];
  int c = __popc(w);
  int off = c;
  for (int s = 1; s < 64; s <<= 1){
    int v = __shfl_up(off, s);
    if (t >= s) off += v;
  }
  int total = __shfl(off, 63);
  off -= c;
  int base = off;
  for (int bit = 0; bit < 32; ++bit){
    if (w & (1u<<bit)){
      if (base < CAP) act_idx[b*CAP+base] = t*32+bit;
      base++;
    }
  }
  if (t == 0) act_cnt[b] = total > CAP ? CAP : total;
}

__global__ void k_scan(const int* __restrict__ act_cnt, int* __restrict__ act_off,
                       int* __restrict__ act_total){
  if (threadIdx.x == 0){
    int s = 0;
    for (int b = 0; b < NB; ++b){ act_off[b] = s; s += act_cnt[b]; }
    act_total[0] = s;
  }
}

// ---------- G[b,ch,j,h] = sum_n dw[b,j,n] * silu(dop*w1[h]+b1[h]) ----------
__launch_bounds__(256)
__global__ void k_gpart(const float* __restrict__ x_t, const float* __restrict__ pc,
                        const float* __restrict__ dop_w1, const float* __restrict__ dop_b1,
                        float* __restrict__ Gp){
  int b = blockIdx.x, ch = blockIdx.y; int t = threadIdx.x;
  __shared__ float sx[J*3];
  __shared__ float w1s[64], b1s[64];
  __shared__ float spx[GPTS], spy[GPTS], spz[GPTS], sdp[GPTS];
  __shared__ float hid[GPTS*65];
  __shared__ float dws[J*129];
  if (t < J*3) sx[t] = x_t[b*J*3 + t];
  if (t < 64){ w1s[t] = dop_w1[t]; b1s[t] = dop_b1[t]; }
  int n0 = ch*GPTS;
  if (t < GPTS){
    const float* p = pc + ((size_t)b*NP + n0 + t)*6;
    float2 f0 = *(const float2*)p;
    float2 f1 = *(const float2*)(p+2);
    spx[t]=f0.x; spy[t]=f0.y; spz[t]=f1.x; sdp[t]=f1.y;
  }
  __syncthreads();
  {
    int p = t>>1, h0 = (t&1)*32;
    float dop = sdp[p];
    #pragma unroll 8
    for (int i = 0; i < 32; ++i){
      int h = h0 + i;
      hid[p*65+h] = siluf(dop*w1s[h]+b1s[h]);
    }
  }
  for (int e = t; e < J*GPTS; e += 256){
    int j = e>>7, p = e&127;
    float x0=sx[j*3], x1=sx[j*3+1], x2=sx[j*3+2];
    float p0=spx[p], p1=spy[p], p2=spz[p];
    float d2 = (x0*x0+x1*x1+x2*x2) + (p0*p0+p1*p1+p2*p2) - 2.f*(x0*p0+x1*p1+x2*p2);
    float dist = sqrtf(fmaxf(d2, 0.f));
    float sig = c_scale[j]*0.05f;
    dws[j*129+p] = expf(-(dist*dist)/(2.f*sig*sig));
  }
  __syncthreads();
  int h = t & 63, jb = t >> 6;
  float acc[7] = {0.f,0.f,0.f,0.f,0.f,0.f,0.f};
  for (int p = 0; p < GPTS; ++p){
    float hv = hid[p*65+h];
    #pragma unroll
    for (int i = 0; i < 7; ++i){
      int j = jb + 4*i;
      if (j < J) acc[i] += dws[j*129+p]*hv;
    }
  }
  float* out = Gp + ((size_t)(b*GCH+ch))*J*64;
  #pragma unroll
  for (int i = 0; i < 7; ++i){
    int j = jb + 4*i;
    if (j < J) out[j*64+h] = acc[i];
  }
}

// ---------- h_dop ----------
__global__ void k_hdop2(const float* __restrict__ Gp, const float* __restrict__ dop_w2,
                        const float* __restrict__ dop_b2, const float* __restrict__ denom_sum,
                        float* __restrict__ h_dop){
  int bj = blockIdx.x; int b = bj/J, j = bj%J; int t = threadIdx.x; // 64
  __shared__ float G[64];
  float g = 0.f;
  for (int c = 0; c < GCH; ++c) g += Gp[((size_t)(b*GCH+c)*J + j)*64 + t];
  G[t] = g; __syncthreads();
  float S = denom_sum[bj];
  float inv = 1.f/(S + 1e-6f);
  float* out = h_dop + (size_t)bj*D;
  for (int u = 0; u < D/64; ++u){
    int d = u*64 + t;
    float acc = 0.f;
    for (int hh = 0; hh < 64; ++hh) acc += G[hh]*dop_w2[hh*D+d];
    out[d] = (acc + S*dop_b2[d]) * inv;
  }
}

// ---------- proj3: fp32 out (+ optional hi/lo) ----------
__global__ void k_proj3(const float* __restrict__ in, const float* __restrict__ w,
                        const float* __restrict__ bias, float* __restrict__ out,
                        u16* __restrict__ oh, u16* __restrict__ ol, int M){
  int idx = blockIdx.x*256 + threadIdx.x;
  if (idx >= M*D) return;
  int r = idx / D, d = idx % D;
  const float* ir = in + r*3;
  float v = ir[0]*w[d] + ir[1]*w[D+d] + ir[2]*w[2*D+d] + bias[d];
  if (out) out[idx] = v;
  if (oh){ u16 h,l; csplit(v,h,l); oh[idx]=h; ol[idx]=l; }
}

__global__ void k_th(const float* __restrict__ t_in, const float* __restrict__ w1,
                     const float* __restrict__ b1, u16* __restrict__ oh, u16* __restrict__ ol){
  int idx = blockIdx.x*256 + threadIdx.x;
  if (idx >= NB*D) return;
  int b = idx / D, d = idx % D;
  float v = siluf(t_in[b]*w1[d] + b1[d]);
  u16 h,l; csplit(v,h,l); oh[idx]=h; ol[idx]=l;
}

__global__ void k_hs2(const float* __restrict__ h_state, u16* __restrict__ oh, u16* __restrict__ ol){
  int idx = blockIdx.x*256 + threadIdx.x;
  if (idx >= NB*J*2*D) return;
  int r = idx / (2*D), c = idx % (2*D);
  int b = r / J, j = r % J;
  float v;
  if (c < D) v = h_state[(size_t)r*D + c];
  else       v = h_state[((size_t)(b*J) + c_parent[j])*D + (c-D)];
  u16 h,l; csplit(v,h,l); oh[idx]=h; ol[idx]=l;
}

__global__ void k_query(const float* __restrict__ h_coarse, const float* __restrict__ h_time,
                        const float* __restrict__ h_dop, const float* __restrict__ h_state,
                        const float* __restrict__ hstruct, const float* __restrict__ jid,
                        const float* __restrict__ mod2, float* __restrict__ x){
  int idx = blockIdx.x*256 + threadIdx.x;
  if (idx >= NB*J*D) return;
  int r = idx / D, d = idx % D;
  int b = r / J, j = r % J;
  float q = h_coarse[idx] + h_time[b*D+d] + h_dop[idx] + h_state[idx] + hstruct[idx] + jid[j*D+d];
  float shift = mod2[(size_t)r*2*D + d];
  float scale = mod2[(size_t)r*2*D + D + d];
  x[idx] = q*(1.f+scale) + shift;
}

// ---------- memory rows for active points (bf16 hi/lo) ----------
__global__ void k_memact(const float* __restrict__ x_t, const float* __restrict__ pc,
                         const float* __restrict__ pc_w, const float* __restrict__ pc_b,
                         const int* __restrict__ act_idx, const int* __restrict__ act_cnt,
                         const int* __restrict__ act_off, u16* __restrict__ mh, u16* __restrict__ ml){
  int b = blockIdx.x / CAP, i = blockIdx.x % CAP;
  if (i >= act_cnt[b]) return;
  int n = act_idx[b*CAP+i];
  int t = threadIdx.x; // 128
  __shared__ float sdw[J];
  __shared__ float spi;
  const float* p = pc + ((size_t)b*NP+n)*6;
  if (t < J){
    float x0 = x_t[(b*J+t)*3+0], x1 = x_t[(b*J+t)*3+1], x2 = x_t[(b*J+t)*3+2];
    float p0=p[0], p1=p[1], p2=p[2];
    float d2 = (x0*x0+x1*x1+x2*x2) + (p0*p0+p1*p1+p2*p2) - 2.f*(x0*p0+x1*p1+x2*p2);
    float dist = sqrtf(fmaxf(d2,0.f));
    float sig = c_scale[t]*0.05f;
    sdw[t] = expf(-(dist*dist)/(2.f*sig*sig));
  }
  __syncthreads();
  if (t == 0){ float m = sdw[0]; for (int k = 1; k < J; ++k) m = fmaxf(m, sdw[k]); spi = m; }
  __syncthreads();
  float pi = spi;
  float p0=p[0],p1=p[1],p2=p[2],p3=p[3],p4=p[4],p5=p[5];
  int g = act_off[b] + i;
  for (int d = t; d < D; d += 128){
    float acc = pc_b[d] + p0*pc_w[d] + p1*pc_w[D+d] + p2*pc_w[2*D+d]
              + p3*pc_w[3*D+d] + p4*pc_w[4*D+d] + p5*pc_w[5*D+d];
    float v = acc * pi;
    u16 h,l; csplit(v,h,l);
    mh[(size_t)g*D + d] = h; ml[(size_t)g*D + d] = l;
  }
}

// ---------- weight conversion: W[K][N] fp32 -> Wt[N][K] bf16 rn ----------
__launch_bounds__(256)
__global__ void k_wconv(const float* __restrict__ W, u16* __restrict__ Wt, int K, int N){
  int k0 = blockIdx.x*64, n0 = blockIdx.y*64;
  size_t zo = (size_t)blockIdx.z*K*N;
  __shared__ float tile[64][65];
  int t = threadIdx.x;
  #pragma unroll
  for (int i = 0; i < 16; ++i){
    int idx = i*256 + t; int k = idx>>6, n = idx&63;
    tile[k][n] = W[zo + (size_t)(k0+k)*N + n0+n];
  }
  __syncthreads();
  #pragma unroll
  for (int i = 0; i < 8; ++i){
    int idx = i*256 + t; int n = idx>>5, kp = (idx&31)*2;
    unsigned pk = (unsigned)f2bf(tile[kp][n]) | ((unsigned)f2bf(tile[kp+1][n])<<16);
    *(unsigned*)&Wt[zo + (size_t)(n0+n)*K + k0+kp] = pk;
  }
}

// ---------- MFMA GEMM: C = act((Ahi+Alo)@Wbf16 + bias [+ res]) ----------
// 64x64 tile, BK=64, 4 waves (2x2) each 32x32. A as bf16 hi/lo [M][K];
// B pre-transposed bf16 [N][K]. XOR-swizzled LDS (conflict-free b128 reads).
__launch_bounds__(256)
__global__ void k_gemm(const u16* __restrict__ Agh, const u16* __restrict__ Agl,
                       const u16* __restrict__ Bt,
                       const float* __restrict__ bias, const float* __restrict__ res,
                       float* __restrict__ Cf, u16* __restrict__ Ch, u16* __restrict__ Cl,
                       int M, int N, int K, int act,
                       const int* __restrict__ Mdev, int ntx){
  int Meff = Mdev ? *Mdev : M;
  int nwg = gridDim.x;
  int q8 = nwg>>3, r8 = nwg&7;
  int xcd = blockIdx.x&7, loc = blockIdx.x>>3;
  int wg = (xcd < r8 ? xcd*(q8+1) : r8*(q8+1)+(xcd-r8)*q8) + loc;
  int row0 = (wg % ntx)*64, col0 = (wg / ntx)*64;
  if (row0 >= Meff) return;

  __shared__ u16 sAh[64*64], sAl[64*64], sBh[64*64];
  int t = threadIdx.x;
  int lane = t&63, w = t>>6, wr = w>>1, wc = w&1;
  int sm = t>>3, kc = t&7;                      // staging: row 0..31 (+32), 16B chunk 0..7
  const u16* a1 = Agh + (size_t)(row0+sm)*K + kc*8;
  const u16* a2 = Agh + (size_t)(row0+sm+32)*K + kc*8;
  const u16* al1 = Agl + (size_t)(row0+sm)*K + kc*8;
  const u16* al2 = Agl + (size_t)(row0+sm+32)*K + kc*8;
  const u16* b1 = Bt + (size_t)(col0+sm)*K + kc*8;
  const u16* b2 = Bt + (size_t)(col0+sm+32)*K + kc*8;
  int o1 = (sm*128 + kc*16) ^ ((sm&7)<<4);
  int o2 = ((sm+32)*128 + kc*16) ^ ((sm&7)<<4);
  uint4 ra1, ra2, rl1, rl2, rb1, rb2;
  auto gload = [&](int kt){
    ra1 = *(const uint4*)(a1 + kt);
    ra2 = *(const uint4*)(a2 + kt);
    rl1 = *(const uint4*)(al1 + kt);
    rl2 = *(const uint4*)(al2 + kt);
    rb1 = *(const uint4*)(b1 + kt);
    rb2 = *(const uint4*)(b2 + kt);
  };
  auto stage = [&](){
    *(uint4*)((char*)sAh + o1) = ra1;
    *(uint4*)((char*)sAh + o2) = ra2;
    *(uint4*)((char*)sAl + o1) = rl1;
    *(uint4*)((char*)sAl + o2) = rl2;
    *(uint4*)((char*)sBh + o1) = rb1;
    *(uint4*)((char*)sBh + o2) = rb2;
  };
  int fr = lane&15, fkb = (lane>>4)*16;
  f32x4 acc[2][2] = {};
  gload(0);
  stage();
  __syncthreads();
  for (int kt = 0; kt < K; kt += 64){
    bool nxt = kt + 64 < K;
    if (nxt) gload(kt + 64);   // prefetch: HBM/L2 latency hides under ds_read+MFMA
    #pragma unroll
    for (int kk = 0; kk < 2; ++kk){
      bf16x8 ah[2], al[2], bh[2];
      #pragma unroll
      for (int m = 0; m < 2; ++m){
        int row = wr*32 + m*16 + fr;
        int adr = (row*128 + kk*64 + fkb) ^ ((row&7)<<4);
        ah[m] = *(const bf16x8*)((char*)sAh + adr);
        al[m] = *(const bf16x8*)((char*)sAl + adr);
      }
      #pragma unroll
      for (int n = 0; n < 2; ++n){
        int rowb = wc*32 + n*16 + fr;
        int adr = (rowb*128 + kk*64 + fkb) ^ ((rowb&7)<<4);
        bh[n] = *(const bf16x8*)((char*)sBh + adr);
      }
      #pragma unroll
      for (int m = 0; m < 2; ++m)
        #pragma unroll
        for (int n = 0; n < 2; ++n){
          acc[m][n] = __builtin_amdgcn_mfma_f32_16x16x32_bf16(al[m], bh[n], acc[m][n], 0,0,0);
          acc[m][n] = __builtin_amdgcn_mfma_f32_16x16x32_bf16(ah[m], bh[n], acc[m][n], 0,0,0);
        }
    }
    if (nxt){
      __syncthreads();
      stage();
      __syncthreads();
    }
  }
  // epilogue: C/D layout col=lane&15, row=(lane>>4)*4+q
  int er = (lane>>4)*4, ec = lane&15;
  #pragma unroll
  for (int m = 0; m < 2; ++m){
    #pragma unroll
    for (int qq = 0; qq < 4; ++qq){
      int r = row0 + wr*32 + m*16 + er + qq;
      if (r >= Meff) continue;
      #pragma unroll
      for (int n = 0; n < 2; ++n){
        int c = col0 + wc*32 + n*16 + ec;
        float v = acc[m][n][qq] + bias[c];
        if (res) v += res[(size_t)r*N + c];
        if (act == 1) v = v/(1.f+expf(-v));
        else if (act == 2) v = fmaxf(v, 0.f);
        if (Cf) Cf[(size_t)r*N + c] = v;
        if (Ch){
          u16 hh, ll; csplit(v, hh, ll);
          Ch[(size_t)r*N + c] = hh;
          Cl[(size_t)r*N + c] = ll;
        }
      }
    }
  }
}

// ---------- LayerNorm over D, per row -> bf16 hi/lo ----------
__global__ void k_ln(const float* __restrict__ x, const float* __restrict__ s,
                     const float* __restrict__ bb, u16* __restrict__ oh, u16* __restrict__ ol){
  int r = blockIdx.x; int t = threadIdx.x; // 256
  const float* xr = x + (size_t)r*D;
  float v0 = xr[t], v1 = xr[t+256];
  __shared__ float red[256];
  red[t] = v0+v1; __syncthreads();
  for (int st = 128; st > 0; st >>= 1){ if (t < st) red[t] += red[t+st]; __syncthreads(); }
  float mu = red[0]/(float)D;
  __syncthreads();
  float d0 = v0-mu, d1 = v1-mu;
  red[t] = d0*d0 + d1*d1; __syncthreads();
  for (int st = 128; st > 0; st >>= 1){ if (t < st) red[t] += red[t+st]; __syncthreads(); }
  float var = red[0]/(float)D;
  float rs = rsqrtf(var + 1e-5f);
  float y0 = d0*rs*s[t] + bb[t];
  float y1 = d1*rs*s[t+256] + bb[t+256];
  u16 h,l;
  csplit(y0,h,l); oh[(size_t)r*D+t]=h;     ol[(size_t)r*D+t]=l;
  csplit(y1,h,l); oh[(size_t)r*D+t+256]=h; ol[(size_t)r*D+t+256]=l;
}

// ---------- self-attn ----------
__launch_bounds__(256)
__global__ void k_selfattn(const float* __restrict__ qkv, u16* __restrict__ oh, u16* __restrict__ ol){
  int bh = blockIdx.x; int b = bh / H, h = bh % H;
  int t = threadIdx.x;
  __shared__ float qs[J*DH], ks[J*DH], vs[J*DH];
  __shared__ float ss[J*J];
  for (int e = t; e < J*DH; e += 256){
    int j = e/DH, d = e%DH;
    const float* base = qkv + (size_t)(b*J+j)*1536 + h*DH + d;
    qs[e] = base[0]; ks[e] = base[512]; vs[e] = base[1024];
  }
  __syncthreads();
  for (int e = t; e < J*J; e += 256){
    int qj = e/J, kk = e%J;
    float acc = 0.f;
    for (int d = 0; d < DH; ++d) acc += qs[qj*DH+d]*ks[kk*DH+d];
    float bias = (qj==kk || c_parent[qj]==kk || c_parent[kk]==qj) ? 0.f : NEGF;
    ss[e] = acc*0.125f + bias;
  }
  __syncthreads();
  if (t < J){
    float m = -3.4e38f;
    for (int k = 0; k < J; ++k) m = fmaxf(m, ss[t*J+k]);
    float sum = 0.f;
    for (int k = 0; k < J; ++k){ float e_ = expf(ss[t*J+k]-m); ss[t*J+k] = e_; sum += e_; }
    float inv = 1.f/sum;
    for (int k = 0; k < J; ++k) ss[t*J+k] *= inv;
  }
  __syncthreads();
  for (int e = t; e < J*DH; e += 256){
    int j = e/DH, d = e%DH;
    float acc = 0.f;
    for (int k = 0; k < J; ++k) acc += ss[j*J+k]*vs[k*DH+d];
    u16 hh,ll; csplit(acc,hh,ll);
    oh[(size_t)(b*J+j)*D + h*DH + d] = hh;
    ol[(size_t)(b*J+j)*D + h*DH + d] = ll;
  }
}

// ---------- cross-attn over active points ----------
__launch_bounds__(256)
__global__ void k_crossattn(const float* __restrict__ qbuf, const float* __restrict__ kv_act,
                            const float* __restrict__ x_t, const float* __restrict__ pc,
                            const int* __restrict__ act_idx, const int* __restrict__ act_cnt,
                            const int* __restrict__ act_off, const int* __restrict__ rescue,
                            const int* __restrict__ allm, u16* __restrict__ oh, u16* __restrict__ ol){
  int bh = blockIdx.x; int b = bh / H, h = bh % H;
  int t = threadIdx.x;
  int cnt = act_cnt[b], off = act_off[b];
  __shared__ float qs[J*DH];
  __shared__ float ks[CAP*DH];
  __shared__ float pxyz[CAP*3];
  __shared__ float sx[J*3];
  __shared__ int sn[CAP];
  __shared__ float ss[J*CAP];
  if (t < J*3) sx[t] = x_t[b*J*3+t];
  for (int e = t; e < J*DH; e += 256)
    qs[e] = qbuf[(size_t)(b*J + e/DH)*D + h*DH + (e%DH)];
  for (int e = t; e < cnt*DH; e += 256){
    int i = e/DH, d = e%DH;
    ks[e] = kv_act[(size_t)(off+i)*1024 + h*DH + d];
  }
  for (int i = t; i < cnt; i += 256){
    int n = act_idx[b*CAP+i]; sn[i] = n;
    const float* p = pc + ((size_t)b*NP+n)*6;
    pxyz[i*3] = p[0]; pxyz[i*3+1] = p[1]; pxyz[i*3+2] = p[2];
  }
  __syncthreads();
  for (int e = t; e < J*cnt; e += 256){
    int j = e/cnt, i = e%cnt;
    float acc = 0.f;
    for (int d = 0; d < DH; ++d) acc += qs[j*DH+d]*ks[i*DH+d];
    float bias;
    if (allm[b*J+j]) bias = (sn[i] == rescue[b*J+j]) ? 0.f : NEGF;
    else {
      float x0=sx[j*3], x1=sx[j*3+1], x2=sx[j*3+2];
      float p0=pxyz[i*3], p1=pxyz[i*3+1], p2=pxyz[i*3+2];
      float d2 = (x0*x0+x1*x1+x2*x2) + (p0*p0+p1*p1+p2*p2) - 2.f*(x0*p0+x1*p1+x2*p2);
      float dist = sqrtf(fmaxf(d2,0.f));
      float ar = c_scale[j]*0.1f;
      bias = (dist > ar) ? NEGF : 0.f;
    }
    ss[j*CAP+i] = acc*0.125f + bias;
  }
  __syncthreads();
  if (t < J){
    float m = -3.4e38f;
    for (int i = 0; i < cnt; ++i) m = fmaxf(m, ss[t*CAP+i]);
    float sum = 0.f;
    for (int i = 0; i < cnt; ++i){ float e_ = expf(ss[t*CAP+i]-m); ss[t*CAP+i] = e_; sum += e_; }
    float inv = 1.f/sum;
    for (int i = 0; i < cnt; ++i) ss[t*CAP+i] *= inv;
  }
  __syncthreads();
  for (int e = t; e < J*DH; e += 256){
    int j = e/DH, d = e%DH;
    float acc = 0.f;
    for (int i = 0; i < cnt; ++i)
      acc += ss[j*CAP+i]*kv_act[(size_t)(off+i)*1024 + 512 + h*DH + d];
    u16 hh,ll; csplit(acc,hh,ll);
    oh[(size_t)(b*J+j)*D + h*DH + d] = hh;
    ol[(size_t)(b*J+j)*D + h*DH + d] = ll;
  }
}

// ---------- final vel projection ----------
__global__ void k_vel(const float* __restrict__ x, const float* __restrict__ vel_w,
                      const float* __restrict__ vel_b, float* __restrict__ out){
  int r = blockIdx.x; int t = threadIdx.x; // 192
  int c = t >> 6; int lane = t & 63;
  float acc = 0.f;
  const float* xr = x + (size_t)r*D;
  for (int d = lane; d < D; d += 64) acc += xr[d]*vel_w[d*3+c];
  for (int s = 32; s > 0; s >>= 1) acc += __shfl_down(acc, s);
  if (lane == 0) out[r*3+c] = acc + vel_b[c];
}

// ============================================================================
static void gemm(const u16* Ah, const u16* Al, const u16* Bt, const float* bias,
                 const float* res, float* Cf, u16* Ch, u16* Cl,
                 int M, int N, int K, int act, const int* Mdev, hipStream_t s){
  int ntx = (M + 63) / 64, nty = N / 64;
  k_gemm<<<ntx*nty, 256, 0, s>>>(Ah, Al, Bt, bias, res, Cf, Ch, Cl, M, N, K, act, Mdev, ntx);
}

extern "C" void kernel_launch(void* const* d_in, const int* in_sizes, int n_in,
                              void* d_out, int out_size, void* d_ws, size_t ws_size,
                              hipStream_t stream){
  const float* x_t        = (const float*)d_in[0];
  const float* t_in       = (const float*)d_in[1];
  const float* coarse     = (const float*)d_in[2];
  const float* radar      = (const float*)d_in[3];
  const float* pc_w       = (const float*)d_in[4];
  const float* pc_b       = (const float*)d_in[5];
  const float* coarse_w   = (const float*)d_in[6];
  const float* coarse_b   = (const float*)d_in[7];
  const float* state_w    = (const float*)d_in[8];
  const float* state_b    = (const float*)d_in[9];
  const float* jid_emb    = (const float*)d_in[10];
  const float* dop_w1     = (const float*)d_in[11];
  const float* dop_b1     = (const float*)d_in[12];
  const float* dop_w2     = (const float*)d_in[13];
  const float* dop_b2     = (const float*)d_in[14];
  const float* time_w1    = (const float*)d_in[15];
  const float* time_b1    = (const float*)d_in[16];
  const float* time_w2    = (const float*)d_in[17];
  const float* time_b2    = (const float*)d_in[18];
  const float* mod_w1     = (const float*)d_in[19];
  const float* mod_b1     = (const float*)d_in[20];
  const float* mod_w2     = (const float*)d_in[21];
  const float* mod_b2     = (const float*)d_in[22];
  const float* diff_w     = (const float*)d_in[23];
  const float* diff_b     = (const float*)d_in[24];
  const float* vel_w      = (const float*)d_in[25];
  const float* vel_b      = (const float*)d_in[26];
  const float* sa_qkv_w   = (const float*)d_in[27];
  const float* sa_qkv_b   = (const float*)d_in[28];
  const float* sa_out_w   = (const float*)d_in[29];
  const float* sa_out_b   = (const float*)d_in[30];
  const float* ca_qkv_w   = (const float*)d_in[31];
  const float* ca_qkv_b   = (const float*)d_in[32];
  const float* ca_out_w   = (const float*)d_in[33];
  const float* ca_out_b   = (const float*)d_in[34];
  const float* ff1_w      = (const float*)d_in[35];
  const float* ff1_b      = (const float*)d_in[36];
  const float* ff2_w      = (const float*)d_in[37];
  const float* ff2_b      = (const float*)d_in[38];
  const float* ln1_s      = (const float*)d_in[39];
  const float* ln1_b      = (const float*)d_in[40];
  const float* ln2_s      = (const float*)d_in[41];
  const float* ln2_b      = (const float*)d_in[42];
  const float* ln3_s      = (const float*)d_in[43];
  const float* ln3_b      = (const float*)d_in[44];
  (void)in_sizes; (void)n_in; (void)out_size; (void)ws_size;

  const int R = NB*J; // 1728

  char* wp = (char*)d_ws;
  auto alloc = [&](size_t bytes)->void*{
    void* r = (void*)wp;
    wp += (bytes + 255) & ~(size_t)255;
    return r;
  };
  float*        denom_sum = (float*)alloc(R*4);
  int*          rescue    = (int*)  alloc(R*4);
  int*          allm      = (int*)  alloc(R*4);
  unsigned int* bitmap    = (unsigned int*)alloc(NB*(NP/32)*4);
  int*          act_idx   = (int*)  alloc(NB*CAP*4);
  int*          act_cnt   = (int*)  alloc(NB*4);
  int*          act_off   = (int*)  alloc(NB*4);
  int*          act_total = (int*)  alloc(64);
  float* Gp       = (float*)alloc((size_t)NB*GCH*J*64*4);
  float* h_dop    = (float*)alloc((size_t)R*D*4);
  float* h_state  = (float*)alloc((size_t)R*D*4);
  float* h_coarse = (float*)alloc((size_t)R*D*4);
  float* hstruct  = (float*)alloc((size_t)R*D*4);
  float* xres     = (float*)alloc((size_t)R*D*4);
  float* qbuf     = (float*)alloc((size_t)R*D*4);
  float* h_time   = (float*)alloc((size_t)NB*D*4);
  float* mod2     = (float*)alloc((size_t)R*2*D*4);
  float* qkv      = (float*)alloc((size_t)R*3*D*4);
  float* kv_act   = (float*)alloc((size_t)NB*CAP*2*D*4);   // 33.5MB; stage-1 aliases hs2 h/l
  // bf16 hi/lo activation buffers
  u16* hsh   = (u16*)alloc((size_t)R*D*2);
  u16* hsl   = (u16*)alloc((size_t)R*D*2);
  u16* hbufh = (u16*)alloc((size_t)R*D*2);
  u16* hbufl = (u16*)alloc((size_t)R*D*2);
  u16* attnoh= (u16*)alloc((size_t)R*D*2);
  u16* attnol= (u16*)alloc((size_t)R*D*2);
  u16* ffhh  = (u16*)alloc((size_t)R*DFF*2);
  u16* ffhl  = (u16*)alloc((size_t)R*DFF*2);
  u16* mah   = (u16*)alloc((size_t)NB*CAP*D*2);
  u16* mal   = (u16*)alloc((size_t)NB*CAP*D*2);
  // transposed bf16 weights [N][K]
  u16* time_w2t = (u16*)alloc((size_t)512*512*2);
  u16* mod_w1t  = (u16*)alloc((size_t)1024*512*2);
  u16* mod_w2t  = (u16*)alloc((size_t)1024*1024*2);
  u16* diff_wt  = (u16*)alloc((size_t)512*1024*2);
  u16* sa_qkv_t = (u16*)alloc((size_t)NLAYER*1536*512*2);
  u16* sa_out_t = (u16*)alloc((size_t)NLAYER*512*512*2);
  u16* ca_qkv_t = (u16*)alloc((size_t)NLAYER*1536*512*2);
  u16* ca_out_t = (u16*)alloc((size_t)NLAYER*512*512*2);
  u16* ff1_t    = (u16*)alloc((size_t)NLAYER*2048*512*2);
  u16* ff2_t    = (u16*)alloc((size_t)NLAYER*512*2048*2);
  // stage-1-only aliases (dead regions reused)
  u16* thh   = attnoh;                 // 64x512 fits; th dead before attn
  u16* thl   = attnol;
  u16* mod1h = ffhh;                   // Rx1024 fits in Rx2048; dead before ff1
  u16* mod1l = ffhl;
  u16* hs2h  = (u16*)kv_act;           // Rx1024 x2 fits in 33.5MB; dead before layer 0 kv
  u16* hs2l  = (u16*)kv_act + (size_t)R*2*D;

  // ---- weight conversion (once per launch) ----
  k_wconv<<<dim3(8, 8, 1),  256, 0, stream>>>(time_w2, time_w2t, 512, 512);
  k_wconv<<<dim3(8, 16, 1), 256, 0, stream>>>(mod_w1, mod_w1t, 512, 1024);
  k_wconv<<<dim3(16, 16, 1),256, 0, stream>>>(mod_w2, mod_w2t, 1024, 1024);
  k_wconv<<<dim3(16, 8, 1), 256, 0, stream>>>(diff_w, diff_wt, 1024, 512);
  k_wconv<<<dim3(8, 24, NLAYER), 256, 0, stream>>>(sa_qkv_w, sa_qkv_t, 512, 1536);
  k_wconv<<<dim3(8, 8, NLAYER),  256, 0, stream>>>(sa_out_w, sa_out_t, 512, 512);
  k_wconv<<<dim3(8, 24, NLAYER), 256, 0, stream>>>(ca_qkv_w, ca_qkv_t, 512, 1536);
  k_wconv<<<dim3(8, 8, NLAYER),  256, 0, stream>>>(ca_out_w, ca_out_t, 512, 512);
  k_wconv<<<dim3(8, 32, NLAYER), 256, 0, stream>>>(ff1_w, ff1_t, 512, 2048);
  k_wconv<<<dim3(32, 8, NLAYER), 256, 0, stream>>>(ff2_w, ff2_t, 2048, 512);

  // ---- stage 0: masks / active set / h_dop ----
  hipMemsetAsync(bitmap, 0, NB*(NP/32)*4, stream);
  k_perj<<<R, 256, 0, stream>>>(x_t, radar, denom_sum, rescue, allm, bitmap);
  k_compact<<<NB, 64, 0, stream>>>(bitmap, act_idx, act_cnt);
  k_scan<<<1, 64, 0, stream>>>(act_cnt, act_off, act_total);
  k_gpart<<<dim3(NB, GCH), 256, 0, stream>>>(x_t, radar, dop_w1, dop_b1, Gp);
  k_hdop2<<<R, 64, 0, stream>>>(Gp, dop_w2, dop_b2, denom_sum, h_dop);

  // ---- stage 1: query build ----
  k_proj3<<<(R*D+255)/256, 256, 0, stream>>>(x_t, state_w, state_b, h_state, hsh, hsl, R);
  k_proj3<<<(R*D+255)/256, 256, 0, stream>>>(coarse, coarse_w, coarse_b, h_coarse, nullptr, nullptr, R);
  k_th<<<(NB*D+255)/256, 256, 0, stream>>>(t_in, time_w1, time_b1, thh, thl);
  gemm(thh, thl, time_w2t, time_b2, nullptr, h_time, nullptr, nullptr, NB, 512, 512, 0, nullptr, stream);
  gemm(hsh, hsl, mod_w1t, mod_b1, nullptr, nullptr, mod1h, mod1l, R, 1024, 512, 1, nullptr, stream);
  gemm(mod1h, mod1l, mod_w2t, mod_b2, nullptr, mod2, nullptr, nullptr, R, 1024, 1024, 0, nullptr, stream);
  k_hs2<<<(R*2*D+255)/256, 256, 0, stream>>>(h_state, hs2h, hs2l);
  gemm(hs2h, hs2l, diff_wt, diff_b, nullptr, hstruct, nullptr, nullptr, R, 512, 1024, 0, nullptr, stream);
  k_query<<<(R*D+255)/256, 256, 0, stream>>>(h_coarse, h_time, h_dop, h_state, hstruct,
                                             jid_emb, mod2, xres);
  k_memact<<<NB*CAP, 128, 0, stream>>>(x_t, radar, pc_w, pc_b, act_idx, act_cnt, act_off, mah, mal);

  // ---- stage 2: transformer layers ----
  for (int l = 0; l < NLAYER; ++l){
    k_ln<<<R, 256, 0, stream>>>(xres, ln1_s + l*D, ln1_b + l*D, hbufh, hbufl);
    gemm(hbufh, hbufl, sa_qkv_t + (size_t)l*1536*512, sa_qkv_b + l*1536, nullptr,
         qkv, nullptr, nullptr, R, 1536, 512, 0, nullptr, stream);
    k_selfattn<<<NB*H, 256, 0, stream>>>(qkv, attnoh, attnol);
    gemm(attnoh, attnol, sa_out_t + (size_t)l*512*512, sa_out_b + l*D, xres,
         xres, nullptr, nullptr, R, 512, 512, 0, nullptr, stream);

    k_ln<<<R, 256, 0, stream>>>(xres, ln2_s + l*D, ln2_b + l*D, hbufh, hbufl);
    gemm(hbufh, hbufl, ca_qkv_t + (size_t)l*1536*512, ca_qkv_b + l*1536, nullptr,
         qbuf, nullptr, nullptr, R, 512, 512, 0, nullptr, stream);
    gemm(mah, mal, ca_qkv_t + (size_t)l*1536*512 + (size_t)512*512, ca_qkv_b + l*1536 + 512,
         nullptr, kv_act, nullptr, nullptr, NB*CAP, 1024, 512, 0, act_total, stream);
    k_crossattn<<<NB*H, 256, 0, stream>>>(qbuf, kv_act, x_t, radar, act_idx, act_cnt,
                                          act_off, rescue, allm, attnoh, attnol);
    gemm(attnoh, attnol, ca_out_t + (size_t)l*512*512, ca_out_b + l*D, xres,
         xres, nullptr, nullptr, R, 512, 512, 0, nullptr, stream);

    k_ln<<<R, 256, 0, stream>>>(xres, ln3_s + l*D, ln3_b + l*D, hbufh, hbufl);
    gemm(hbufh, hbufl, ff1_t + (size_t)l*2048*512, ff1_b + l*DFF, nullptr,
         nullptr, ffhh, ffhl, R, 2048, 512, 2, nullptr, stream);
    gemm(ffhh, ffhl, ff2_t + (size_t)l*512*2048, ff2_b + l*D, xres,
         xres, nullptr, nullptr, R, 512, 2048, 0, nullptr, stream);
  }

  k_vel<<<R, 192, 0, stream>>>(xres, vel_w, vel_b, (float*)d_out);
}

// Round 5
// 1217.436 us; speedup vs baseline: 2.6702x; 1.1368x over previous
//
#include <hip/hip_runtime.h>

#define J 27
#define D 512
#define H 8
#define DH 64
#define NLAYER 6
#define DFF 2048
#define NB 64
#define NP 2048
#define CAP 128
#define GCH 16
#define GPTS 128
#define NEGF -1000000000.0f

typedef unsigned short u16;
typedef __attribute__((ext_vector_type(8))) __bf16 bf16x8;
typedef __attribute__((ext_vector_type(4))) float f32x4;

__constant__ int c_parent[J] = {0,0,1,2,3,4,5,6,7,8,8,3,11,12,13,14,15,15,0,18,19,20,0,22,23,24,3};
__constant__ float c_scale[J] = {0.6f,0.6f,0.6f,0.6f,1.f,1.f,1.f,1.f,1.f,1.5f,1.5f,1.f,1.f,1.f,1.f,1.f,
                                 1.5f,1.5f,0.6f,1.f,1.5f,1.5f,0.6f,1.f,1.5f,1.5f,1.5f};

__device__ __forceinline__ float siluf(float x){ return x/(1.f+expf(-x)); }

__device__ __forceinline__ u16 f2bf(float f){
  union { float f; unsigned u; } x; x.f = f;
  unsigned r = x.u + 0x7FFFu + ((x.u >> 16) & 1u);
  return (u16)(r >> 16);
}
__device__ __forceinline__ float bf2f(u16 h){
  union { unsigned u; float f; } x; x.u = ((unsigned)h) << 16; return x.f;
}
__device__ __forceinline__ void csplit(float v, u16 &h, u16 &l){
  h = f2bf(v);
  l = f2bf(v - bf2f(h));
}

// ---------- per (b,j): denom sum, rescue idx, allmask, active-bitmap marks ----------
__global__ void k_perj(const float* __restrict__ x_t, const float* __restrict__ pc,
                       float* __restrict__ denom_sum, int* __restrict__ rescue,
                       int* __restrict__ allm, unsigned int* __restrict__ bitmap){
  int bj = blockIdx.x; int b = bj / J, j = bj % J;
  int t = threadIdx.x;
  float x0 = x_t[(b*J+j)*3+0];
  float x1 = x_t[(b*J+j)*3+1];
  float x2 = x_t[(b*J+j)*3+2];
  float sx = x0*x0+x1*x1+x2*x2;
  float ar = c_scale[j]*0.1f;
  float sig = ar*0.5f;
  float twos2 = 2.f*sig*sig;
  float sum = 0.f, bmin = 3.4e38f; int bidx = NP; int any = 0;
  for (int n = t; n < NP; n += 256){
    const float* p = pc + ((size_t)b*NP + n)*6;
    float p0=p[0], p1=p[1], p2=p[2];
    float d2 = sx + (p0*p0+p1*p1+p2*p2) - 2.f*(x0*p0+x1*p1+x2*p2);
    float dist = sqrtf(fmaxf(d2, 0.f));
    sum += expf(-(dist*dist)/twos2);
    if (dist < bmin){ bmin = dist; bidx = n; }
    if (dist <= ar){ any = 1; atomicOr(&bitmap[b*(NP/32)+(n>>5)], 1u<<(n&31)); }
  }
  __shared__ float ssum[256]; __shared__ float smin[256];
  __shared__ int sidx[256]; __shared__ int sany[256];
  ssum[t]=sum; smin[t]=bmin; sidx[t]=bidx; sany[t]=any;
  __syncthreads();
  for (int s = 128; s > 0; s >>= 1){
    if (t < s){
      ssum[t] += ssum[t+s];
      if (smin[t+s] < smin[t] || (smin[t+s]==smin[t] && sidx[t+s] < sidx[t])){ smin[t]=smin[t+s]; sidx[t]=sidx[t+s]; }
      sany[t] |= sany[t+s];
    }
    __syncthreads();
  }
  if (t == 0){
    denom_sum[bj] = ssum[0];
    rescue[bj] = sidx[0];
    allm[bj] = sany[0] ? 0 : 1;
    if (!sany[0]) atomicOr(&bitmap[b*(NP/32)+(sidx[0]>>5)], 1u<<(sidx[0]&31));
  }
}

// ---------- ordered compaction of active bitmap ----------
__global__ void k_compact(const unsigned int* __restrict__ bitmap, int* __restrict__ act_idx,
                          int* __restrict__ act_cnt){
  int b = blockIdx.x; int t = threadIdx.x; // 64 = 1 wave
  unsigned int w = bitmap[b*(NP/32)+t];
  int c = __popc(w);
  int off = c;
  for (int s = 1; s < 64; s <<= 1){
    int v = __shfl_up(off, s);
    if (t >= s) off += v;
  }
  int total = __shfl(off, 63);
  off -= c;
  int base = off;
  for (int bit = 0; bit < 32; ++bit){
    if (w & (1u<<bit)){
      if (base < CAP) act_idx[b*CAP+base] = t*32+bit;
      base++;
    }
  }
  if (t == 0) act_cnt[b] = total > CAP ? CAP : total;
}

__global__ void k_scan(const int* __restrict__ act_cnt, int* __restrict__ act_off,
                       int* __restrict__ act_total){
  if (threadIdx.x == 0){
    int s = 0;
    for (int b = 0; b < NB; ++b){ act_off[b] = s; s += act_cnt[b]; }
    act_total[0] = s;
  }
}

// ---------- G[b,ch,j,h] = sum_n dw[b,j,n] * silu(dop*w1[h]+b1[h]) ----------
__launch_bounds__(256)
__global__ void k_gpart(const float* __restrict__ x_t, const float* __restrict__ pc,
                        const float* __restrict__ dop_w1, const float* __restrict__ dop_b1,
                        float* __restrict__ Gp){
  int b = blockIdx.x, ch = blockIdx.y; int t = threadIdx.x;
  __shared__ float sx[J*3];
  __shared__ float w1s[64], b1s[64];
  __shared__ float spx[GPTS], spy[GPTS], spz[GPTS], sdp[GPTS];
  __shared__ float hid[GPTS*65];
  __shared__ float dws[J*129];
  if (t < J*3) sx[t] = x_t[b*J*3 + t];
  if (t < 64){ w1s[t] = dop_w1[t]; b1s[t] = dop_b1[t]; }
  int n0 = ch*GPTS;
  if (t < GPTS){
    const float* p = pc + ((size_t)b*NP + n0 + t)*6;
    float2 f0 = *(const float2*)p;
    float2 f1 = *(const float2*)(p+2);
    spx[t]=f0.x; spy[t]=f0.y; spz[t]=f1.x; sdp[t]=f1.y;
  }
  __syncthreads();
  {
    int p = t>>1, h0 = (t&1)*32;
    float dop = sdp[p];
    #pragma unroll 8
    for (int i = 0; i < 32; ++i){
      int h = h0 + i;
      hid[p*65+h] = siluf(dop*w1s[h]+b1s[h]);
    }
  }
  for (int e = t; e < J*GPTS; e += 256){
    int j = e>>7, p = e&127;
    float x0=sx[j*3], x1=sx[j*3+1], x2=sx[j*3+2];
    float p0=spx[p], p1=spy[p], p2=spz[p];
    float d2 = (x0*x0+x1*x1+x2*x2) + (p0*p0+p1*p1+p2*p2) - 2.f*(x0*p0+x1*p1+x2*p2);
    float dist = sqrtf(fmaxf(d2, 0.f));
    float sig = c_scale[j]*0.05f;
    dws[j*129+p] = expf(-(dist*dist)/(2.f*sig*sig));
  }
  __syncthreads();
  int h = t & 63, jb = t >> 6;
  float acc[7] = {0.f,0.f,0.f,0.f,0.f,0.f,0.f};
  for (int p = 0; p < GPTS; ++p){
    float hv = hid[p*65+h];
    #pragma unroll
    for (int i = 0; i < 7; ++i){
      int j = jb + 4*i;
      if (j < J) acc[i] += dws[j*129+p]*hv;
    }
  }
  float* out = Gp + ((size_t)(b*GCH+ch))*J*64;
  #pragma unroll
  for (int i = 0; i < 7; ++i){
    int j = jb + 4*i;
    if (j < J) out[j*64+h] = acc[i];
  }
}

// ---------- reduce Gp chunks -> G[bj][64] ----------
__global__ void k_gred(const float* __restrict__ Gp, float* __restrict__ G){
  int idx = blockIdx.x*256 + threadIdx.x;   // < R*64
  int bj = idx >> 6, h = idx & 63;
  int b = bj / J, j = bj % J;
  float s = 0.f;
  #pragma unroll
  for (int c = 0; c < GCH; ++c) s += Gp[((size_t)(b*GCH+c)*J + j)*64 + h];
  G[idx] = s;
}

// ---------- h_dop: one block per (b, d-half); G in LDS; 27 reg accumulators ----------
__launch_bounds__(256)
__global__ void k_hdop2(const float* __restrict__ G, const float* __restrict__ dop_w2,
                        const float* __restrict__ dop_b2, const float* __restrict__ denom_sum,
                        float* __restrict__ h_dop){
  int b = blockIdx.x, half = blockIdx.y;
  int t = threadIdx.x;
  int d = half*256 + t;
  __shared__ float sG[J*64];
  __shared__ float sS[J], sI[J];
  for (int e = t; e < J*64; e += 256) sG[e] = G[(size_t)b*J*64 + e];
  if (t < J){ float S = denom_sum[b*J+t]; sS[t] = S; sI[t] = 1.f/(S+1e-6f); }
  __syncthreads();
  float acc[J];
  #pragma unroll
  for (int j = 0; j < J; ++j) acc[j] = 0.f;
  for (int h = 0; h < 64; ++h){
    float wv = dop_w2[h*D + d];
    #pragma unroll
    for (int j = 0; j < J; ++j) acc[j] += sG[j*64+h]*wv;
  }
  float b2 = dop_b2[d];
  #pragma unroll
  for (int j = 0; j < J; ++j)
    h_dop[(size_t)(b*J+j)*D + d] = (acc[j] + sS[j]*b2)*sI[j];
}

// ---------- merged stage-1 elementwise: h_state(+h/l), h_coarse, th(h/l) ----------
__global__ void k_stage1(const float* __restrict__ x_t, const float* __restrict__ state_w,
                         const float* __restrict__ state_b,
                         const float* __restrict__ coarse, const float* __restrict__ coarse_w,
                         const float* __restrict__ coarse_b,
                         const float* __restrict__ t_in, const float* __restrict__ time_w1,
                         const float* __restrict__ time_b1,
                         float* __restrict__ h_state, u16* __restrict__ hsh, u16* __restrict__ hsl,
                         float* __restrict__ h_coarse, u16* __restrict__ thh, u16* __restrict__ thl){
  const int RD = NB*J*D;
  int idx = blockIdx.x*256 + threadIdx.x;
  if (idx < RD){
    int r = idx / D, d = idx % D;
    const float* ir = x_t + r*3;
    float v = ir[0]*state_w[d] + ir[1]*state_w[D+d] + ir[2]*state_w[2*D+d] + state_b[d];
    h_state[idx] = v;
    u16 h,l; csplit(v,h,l); hsh[idx]=h; hsl[idx]=l;
  } else if (idx < 2*RD){
    int k = idx - RD;
    int r = k / D, d = k % D;
    const float* ir = coarse + r*3;
    h_coarse[k] = ir[0]*coarse_w[d] + ir[1]*coarse_w[D+d] + ir[2]*coarse_w[2*D+d] + coarse_b[d];
  } else if (idx < 2*RD + NB*D){
    int k = idx - 2*RD;
    int b = k / D, d = k % D;
    float v = siluf(t_in[b]*time_w1[d] + time_b1[d]);
    u16 h,l; csplit(v,h,l); thh[k]=h; thl[k]=l;
  }
}

__global__ void k_hs2(const float* __restrict__ h_state, u16* __restrict__ oh, u16* __restrict__ ol){
  int idx = blockIdx.x*256 + threadIdx.x;
  if (idx >= NB*J*2*D) return;
  int r = idx / (2*D), c = idx % (2*D);
  int b = r / J, j = r % J;
  float v;
  if (c < D) v = h_state[(size_t)r*D + c];
  else       v = h_state[((size_t)(b*J) + c_parent[j])*D + (c-D)];
  u16 h,l; csplit(v,h,l); oh[idx]=h; ol[idx]=l;
}

__global__ void k_query(const float* __restrict__ h_coarse, const float* __restrict__ h_time,
                        const float* __restrict__ h_dop, const float* __restrict__ h_state,
                        const float* __restrict__ hstruct, const float* __restrict__ jid,
                        const float* __restrict__ mod2, float* __restrict__ x){
  int idx = blockIdx.x*256 + threadIdx.x;
  if (idx >= NB*J*D) return;
  int r = idx / D, d = idx % D;
  int b = r / J, j = r % J;
  float q = h_coarse[idx] + h_time[b*D+d] + h_dop[idx] + h_state[idx] + hstruct[idx] + jid[j*D+d];
  float shift = mod2[(size_t)r*2*D + d];
  float scale = mod2[(size_t)r*2*D + D + d];
  x[idx] = q*(1.f+scale) + shift;
}

// ---------- memory rows for active points (bf16 hi/lo) ----------
__global__ void k_memact(const float* __restrict__ x_t, const float* __restrict__ pc,
                         const float* __restrict__ pc_w, const float* __restrict__ pc_b,
                         const int* __restrict__ act_idx, const int* __restrict__ act_cnt,
                         const int* __restrict__ act_off, u16* __restrict__ mh, u16* __restrict__ ml){
  int b = blockIdx.x / CAP, i = blockIdx.x % CAP;
  if (i >= act_cnt[b]) return;
  int n = act_idx[b*CAP+i];
  int t = threadIdx.x; // 128
  __shared__ float sdw[J];
  __shared__ float spi;
  const float* p = pc + ((size_t)b*NP+n)*6;
  if (t < J){
    float x0 = x_t[(b*J+t)*3+0], x1 = x_t[(b*J+t)*3+1], x2 = x_t[(b*J+t)*3+2];
    float p0=p[0], p1=p[1], p2=p[2];
    float d2 = (x0*x0+x1*x1+x2*x2) + (p0*p0+p1*p1+p2*p2) - 2.f*(x0*p0+x1*p1+x2*p2);
    float dist = sqrtf(fmaxf(d2,0.f));
    float sig = c_scale[t]*0.05f;
    sdw[t] = expf(-(dist*dist)/(2.f*sig*sig));
  }
  __syncthreads();
  if (t == 0){ float m = sdw[0]; for (int k = 1; k < J; ++k) m = fmaxf(m, sdw[k]); spi = m; }
  __syncthreads();
  float pi = spi;
  float p0=p[0],p1=p[1],p2=p[2],p3=p[3],p4=p[4],p5=p[5];
  int g = act_off[b] + i;
  for (int d = t; d < D; d += 128){
    float acc = pc_b[d] + p0*pc_w[d] + p1*pc_w[D+d] + p2*pc_w[2*D+d]
              + p3*pc_w[3*D+d] + p4*pc_w[4*D+d] + p5*pc_w[5*D+d];
    float v = acc * pi;
    u16 h,l; csplit(v,h,l);
    mh[(size_t)g*D + d] = h; ml[(size_t)g*D + d] = l;
  }
}

// ---------- weight conversion: W[K][N] fp32 -> Wt[N][K] bf16 rn ----------
__launch_bounds__(256)
__global__ void k_wconv(const float* __restrict__ W, u16* __restrict__ Wt, int K, int N){
  int k0 = blockIdx.x*64, n0 = blockIdx.y*64;
  size_t zo = (size_t)blockIdx.z*K*N;
  __shared__ float tile[64][65];
  int t = threadIdx.x;
  #pragma unroll
  for (int i = 0; i < 16; ++i){
    int idx = i*256 + t; int k = idx>>6, n = idx&63;
    tile[k][n] = W[zo + (size_t)(k0+k)*N + n0+n];
  }
  __syncthreads();
  #pragma unroll
  for (int i = 0; i < 8; ++i){
    int idx = i*256 + t; int n = idx>>5, kp = (idx&31)*2;
    unsigned pk = (unsigned)f2bf(tile[kp][n]) | ((unsigned)f2bf(tile[kp+1][n])<<16);
    *(unsigned*)&Wt[zo + (size_t)(n0+n)*K + k0+kp] = pk;
  }
}

// ---------- MFMA GEMM: C = act((Ahi+Alo)@Wbf16 + bias [+ res]) ----------
// tile TM x 64, BK=64, 4 waves. TM=64: waves 2x2 of 32x32. TM=32: waves 2x2 of 16x32.
// A bf16 hi/lo [M][K]; B pre-transposed bf16 [N][K]. XOR-swizzled LDS.
template<int TM>
__launch_bounds__(256)
__global__ void k_gemm(const u16* __restrict__ Agh, const u16* __restrict__ Agl,
                       const u16* __restrict__ Bt,
                       const float* __restrict__ bias, const float* __restrict__ res,
                       float* __restrict__ Cf, u16* __restrict__ Ch, u16* __restrict__ Cl,
                       int M, int N, int K, int act,
                       const int* __restrict__ Mdev, int ntx){
  int Meff = Mdev ? *Mdev : M;
  int nwg = gridDim.x;
  int q8 = nwg>>3, r8 = nwg&7;
  int xcd = blockIdx.x&7, loc = blockIdx.x>>3;
  int wg = (xcd < r8 ? xcd*(q8+1) : r8*(q8+1)+(xcd-r8)*q8) + loc;
  int row0 = (wg % ntx)*TM, col0 = (wg / ntx)*64;
  if (row0 >= Meff) return;

  constexpr int MFR = TM/32;   // m-frags per wave
  constexpr int RW  = TM/2;    // wave row span
  __shared__ u16 sAh[TM*64], sAl[TM*64], sBh[64*64];
  int t = threadIdx.x;
  int lane = t&63, w = t>>6, wr = w>>1, wc = w&1;
  int sm = t>>3, kc = t&7;   // sm 0..31
  const u16* pAh1 = Agh + (size_t)(row0+sm)*K + kc*8;
  const u16* pAl1 = Agl + (size_t)(row0+sm)*K + kc*8;
  const u16* pAh2 = (TM==64) ? Agh + (size_t)(row0+sm+32)*K + kc*8 : pAh1;
  const u16* pAl2 = (TM==64) ? Agl + (size_t)(row0+sm+32)*K + kc*8 : pAl1;
  const u16* pB1 = Bt + (size_t)(col0+sm)*K + kc*8;
  const u16* pB2 = Bt + (size_t)(col0+sm+32)*K + kc*8;
  int o1 = (sm*128 + kc*16) ^ ((sm&7)<<4);
  int o2 = ((sm+32)*128 + kc*16) ^ ((sm&7)<<4);
  uint4 ra1, rl1, ra2, rl2, rb1, rb2;
  auto gload = [&](int kt){
    ra1 = *(const uint4*)(pAh1 + kt);
    rl1 = *(const uint4*)(pAl1 + kt);
    if constexpr (TM==64){
      ra2 = *(const uint4*)(pAh2 + kt);
      rl2 = *(const uint4*)(pAl2 + kt);
    }
    rb1 = *(const uint4*)(pB1 + kt);
    rb2 = *(const uint4*)(pB2 + kt);
  };
  auto stage = [&](){
    *(uint4*)((char*)sAh + o1) = ra1;
    *(uint4*)((char*)sAl + o1) = rl1;
    if constexpr (TM==64){
      *(uint4*)((char*)sAh + o2) = ra2;
      *(uint4*)((char*)sAl + o2) = rl2;
    }
    *(uint4*)((char*)sBh + o1) = rb1;
    *(uint4*)((char*)sBh + o2) = rb2;
  };
  int fr = lane&15, fkb = (lane>>4)*16;
  f32x4 acc[MFR][2] = {};
  gload(0);
  stage();
  __syncthreads();
  for (int kt = 0; kt < K; kt += 64){
    bool nxt = kt + 64 < K;
    if (nxt) gload(kt + 64);
    #pragma unroll
    for (int kk = 0; kk < 2; ++kk){
      bf16x8 ah[MFR], al[MFR], bh[2];
      #pragma unroll
      for (int m = 0; m < MFR; ++m){
        int row = wr*RW + m*16 + fr;
        int adr = (row*128 + kk*64 + fkb) ^ ((row&7)<<4);
        ah[m] = *(const bf16x8*)((char*)sAh + adr);
        al[m] = *(const bf16x8*)((char*)sAl + adr);
      }
      #pragma unroll
      for (int n = 0; n < 2; ++n){
        int rowb = wc*32 + n*16 + fr;
        int adr = (rowb*128 + kk*64 + fkb) ^ ((rowb&7)<<4);
        bh[n] = *(const bf16x8*)((char*)sBh + adr);
      }
      #pragma unroll
      for (int m = 0; m < MFR; ++m)
        #pragma unroll
        for (int n = 0; n < 2; ++n){
          acc[m][n] = __builtin_amdgcn_mfma_f32_16x16x32_bf16(al[m], bh[n], acc[m][n], 0,0,0);
          acc[m][n] = __builtin_amdgcn_mfma_f32_16x16x32_bf16(ah[m], bh[n], acc[m][n], 0,0,0);
        }
    }
    if (nxt){
      __syncthreads();
      stage();
      __syncthreads();
    }
  }
  int er = (lane>>4)*4, ec = lane&15;
  #pragma unroll
  for (int m = 0; m < MFR; ++m){
    #pragma unroll
    for (int qq = 0; qq < 4; ++qq){
      int r = row0 + wr*RW + m*16 + er + qq;
      if (r >= Meff) continue;
      #pragma unroll
      for (int n = 0; n < 2; ++n){
        int c = col0 + wc*32 + n*16 + ec;
        float v = acc[m][n][qq] + bias[c];
        if (res) v += res[(size_t)r*N + c];
        if (act == 1) v = v/(1.f+expf(-v));
        else if (act == 2) v = fmaxf(v, 0.f);
        if (Cf) Cf[(size_t)r*N + c] = v;
        if (Ch){
          u16 hh, ll; csplit(v, hh, ll);
          Ch[(size_t)r*N + c] = hh;
          Cl[(size_t)r*N + c] = ll;
        }
      }
    }
  }
}

// ---------- LayerNorm over D, per row -> bf16 hi/lo ----------
__global__ void k_ln(const float* __restrict__ x, const float* __restrict__ s,
                     const float* __restrict__ bb, u16* __restrict__ oh, u16* __restrict__ ol){
  int r = blockIdx.x; int t = threadIdx.x; // 256
  const float* xr = x + (size_t)r*D;
  float v0 = xr[t], v1 = xr[t+256];
  __shared__ float red[256];
  red[t] = v0+v1; __syncthreads();
  for (int st = 128; st > 0; st >>= 1){ if (t < st) red[t] += red[t+st]; __syncthreads(); }
  float mu = red[0]/(float)D;
  __syncthreads();
  float d0 = v0-mu, d1 = v1-mu;
  red[t] = d0*d0 + d1*d1; __syncthreads();
  for (int st = 128; st > 0; st >>= 1){ if (t < st) red[t] += red[t+st]; __syncthreads(); }
  float var = red[0]/(float)D;
  float rs = rsqrtf(var + 1e-5f);
  float y0 = d0*rs*s[t] + bb[t];
  float y1 = d1*rs*s[t+256] + bb[t+256];
  u16 h,l;
  csplit(y0,h,l); oh[(size_t)r*D+t]=h;     ol[(size_t)r*D+t]=l;
  csplit(y1,h,l); oh[(size_t)r*D+t+256]=h; ol[(size_t)r*D+t+256]=l;
}

// ---------- self-attn ----------
__launch_bounds__(256)
__global__ void k_selfattn(const float* __restrict__ qkv, u16* __restrict__ oh, u16* __restrict__ ol){
  int bh = blockIdx.x; int b = bh / H, h = bh % H;
  int t = threadIdx.x;
  __shared__ float qs[J*DH], ks[J*DH], vs[J*DH];
  __shared__ float ss[J*J];
  for (int e = t; e < J*DH; e += 256){
    int j = e/DH, d = e%DH;
    const float* base = qkv + (size_t)(b*J+j)*1536 + h*DH + d;
    qs[e] = base[0]; ks[e] = base[512]; vs[e] = base[1024];
  }
  __syncthreads();
  for (int e = t; e < J*J; e += 256){
    int qj = e/J, kk = e%J;
    float acc = 0.f;
    for (int d = 0; d < DH; ++d) acc += qs[qj*DH+d]*ks[kk*DH+d];
    float bias = (qj==kk || c_parent[qj]==kk || c_parent[kk]==qj) ? 0.f : NEGF;
    ss[e] = acc*0.125f + bias;
  }
  __syncthreads();
  if (t < J){
    float m = -3.4e38f;
    for (int k = 0; k < J; ++k) m = fmaxf(m, ss[t*J+k]);
    float sum = 0.f;
    for (int k = 0; k < J; ++k){ float e_ = expf(ss[t*J+k]-m); ss[t*J+k] = e_; sum += e_; }
    float inv = 1.f/sum;
    for (int k = 0; k < J; ++k) ss[t*J+k] *= inv;
  }
  __syncthreads();
  for (int e = t; e < J*DH; e += 256){
    int j = e/DH, d = e%DH;
    float acc = 0.f;
    for (int k = 0; k < J; ++k) acc += ss[j*J+k]*vs[k*DH+d];
    u16 hh,ll; csplit(acc,hh,ll);
    oh[(size_t)(b*J+j)*D + h*DH + d] = hh;
    ol[(size_t)(b*J+j)*D + h*DH + d] = ll;
  }
}

// ---------- cross-attn over active points ----------
__launch_bounds__(256)
__global__ void k_crossattn(const float* __restrict__ qbuf, const float* __restrict__ kv_act,
                            const float* __restrict__ x_t, const float* __restrict__ pc,
                            const int* __restrict__ act_idx, const int* __restrict__ act_cnt,
                            const int* __restrict__ act_off, const int* __restrict__ rescue,
                            const int* __restrict__ allm, u16* __restrict__ oh, u16* __restrict__ ol){
  int bh = blockIdx.x; int b = bh / H, h = bh % H;
  int t = threadIdx.x;
  int cnt = act_cnt[b], off = act_off[b];
  __shared__ float qs[J*DH];
  __shared__ float ks[CAP*DH];
  __shared__ float pxyz[CAP*3];
  __shared__ float sx[J*3];
  __shared__ int sn[CAP];
  __shared__ float ss[J*CAP];
  if (t < J*3) sx[t] = x_t[b*J*3+t];
  for (int e = t; e < J*DH; e += 256)
    qs[e] = qbuf[(size_t)(b*J + e/DH)*D + h*DH + (e%DH)];
  for (int e = t; e < cnt*DH; e += 256){
    int i = e/DH, d = e%DH;
    ks[e] = kv_act[(size_t)(off+i)*1024 + h*DH + d];
  }
  for (int i = t; i < cnt; i += 256){
    int n = act_idx[b*CAP+i]; sn[i] = n;
    const float* p = pc + ((size_t)b*NP+n)*6;
    pxyz[i*3] = p[0]; pxyz[i*3+1] = p[1]; pxyz[i*3+2] = p[2];
  }
  __syncthreads();
  for (int e = t; e < J*cnt; e += 256){
    int j = e/cnt, i = e%cnt;
    float acc = 0.f;
    for (int d = 0; d < DH; ++d) acc += qs[j*DH+d]*ks[i*DH+d];
    float bias;
    if (allm[b*J+j]) bias = (sn[i] == rescue[b*J+j]) ? 0.f : NEGF;
    else {
      float x0=sx[j*3], x1=sx[j*3+1], x2=sx[j*3+2];
      float p0=pxyz[i*3], p1=pxyz[i*3+1], p2=pxyz[i*3+2];
      float d2 = (x0*x0+x1*x1+x2*x2) + (p0*p0+p1*p1+p2*p2) - 2.f*(x0*p0+x1*p1+x2*p2);
      float dist = sqrtf(fmaxf(d2,0.f));
      float ar = c_scale[j]*0.1f;
      bias = (dist > ar) ? NEGF : 0.f;
    }
    ss[j*CAP+i] = acc*0.125f + bias;
  }
  __syncthreads();
  if (t < J){
    float m = -3.4e38f;
    for (int i = 0; i < cnt; ++i) m = fmaxf(m, ss[t*CAP+i]);
    float sum = 0.f;
    for (int i = 0; i < cnt; ++i){ float e_ = expf(ss[t*CAP+i]-m); ss[t*CAP+i] = e_; sum += e_; }
    float inv = 1.f/sum;
    for (int i = 0; i < cnt; ++i) ss[t*CAP+i] *= inv;
  }
  __syncthreads();
  for (int e = t; e < J*DH; e += 256){
    int j = e/DH, d = e%DH;
    float acc = 0.f;
    for (int i = 0; i < cnt; ++i)
      acc += ss[j*CAP+i]*kv_act[(size_t)(off+i)*1024 + 512 + h*DH + d];
    u16 hh,ll; csplit(acc,hh,ll);
    oh[(size_t)(b*J+j)*D + h*DH + d] = hh;
    ol[(size_t)(b*J+j)*D + h*DH + d] = ll;
  }
}

// ---------- final vel projection ----------
__global__ void k_vel(const float* __restrict__ x, const float* __restrict__ vel_w,
                      const float* __restrict__ vel_b, float* __restrict__ out){
  int r = blockIdx.x; int t = threadIdx.x; // 192
  int c = t >> 6; int lane = t & 63;
  float acc = 0.f;
  const float* xr = x + (size_t)r*D;
  for (int d = lane; d < D; d += 64) acc += xr[d]*vel_w[d*3+c];
  for (int s = 32; s > 0; s >>= 1) acc += __shfl_down(acc, s);
  if (lane == 0) out[r*3+c] = acc + vel_b[c];
}

// ============================================================================
static void gemm(const u16* Ah, const u16* Al, const u16* Bt, const float* bias,
                 const float* res, float* Cf, u16* Ch, u16* Cl,
                 int M, int N, int K, int act, const int* Mdev, int tm, hipStream_t s){
  if (tm == 32){
    int ntx = (M + 31) / 32;
    k_gemm<32><<<ntx*(N/64), 256, 0, s>>>(Ah, Al, Bt, bias, res, Cf, Ch, Cl, M, N, K, act, Mdev, ntx);
  } else {
    int ntx = (M + 63) / 64;
    k_gemm<64><<<ntx*(N/64), 256, 0, s>>>(Ah, Al, Bt, bias, res, Cf, Ch, Cl, M, N, K, act, Mdev, ntx);
  }
}

extern "C" void kernel_launch(void* const* d_in, const int* in_sizes, int n_in,
                              void* d_out, int out_size, void* d_ws, size_t ws_size,
                              hipStream_t stream){
  const float* x_t        = (const float*)d_in[0];
  const float* t_in       = (const float*)d_in[1];
  const float* coarse     = (const float*)d_in[2];
  const float* radar      = (const float*)d_in[3];
  const float* pc_w       = (const float*)d_in[4];
  const float* pc_b       = (const float*)d_in[5];
  const float* coarse_w   = (const float*)d_in[6];
  const float* coarse_b   = (const float*)d_in[7];
  const float* state_w    = (const float*)d_in[8];
  const float* state_b    = (const float*)d_in[9];
  const float* jid_emb    = (const float*)d_in[10];
  const float* dop_w1     = (const float*)d_in[11];
  const float* dop_b1     = (const float*)d_in[12];
  const float* dop_w2     = (const float*)d_in[13];
  const float* dop_b2     = (const float*)d_in[14];
  const float* time_w1    = (const float*)d_in[15];
  const float* time_b1    = (const float*)d_in[16];
  const float* time_w2    = (const float*)d_in[17];
  const float* time_b2    = (const float*)d_in[18];
  const float* mod_w1     = (const float*)d_in[19];
  const float* mod_b1     = (const float*)d_in[20];
  const float* mod_w2     = (const float*)d_in[21];
  const float* mod_b2     = (const float*)d_in[22];
  const float* diff_w     = (const float*)d_in[23];
  const float* diff_b     = (const float*)d_in[24];
  const float* vel_w      = (const float*)d_in[25];
  const float* vel_b      = (const float*)d_in[26];
  const float* sa_qkv_w   = (const float*)d_in[27];
  const float* sa_qkv_b   = (const float*)d_in[28];
  const float* sa_out_w   = (const float*)d_in[29];
  const float* sa_out_b   = (const float*)d_in[30];
  const float* ca_qkv_w   = (const float*)d_in[31];
  const float* ca_qkv_b   = (const float*)d_in[32];
  const float* ca_out_w   = (const float*)d_in[33];
  const float* ca_out_b   = (const float*)d_in[34];
  const float* ff1_w      = (const float*)d_in[35];
  const float* ff1_b      = (const float*)d_in[36];
  const float* ff2_w      = (const float*)d_in[37];
  const float* ff2_b      = (const float*)d_in[38];
  const float* ln1_s      = (const float*)d_in[39];
  const float* ln1_b      = (const float*)d_in[40];
  const float* ln2_s      = (const float*)d_in[41];
  const float* ln2_b      = (const float*)d_in[42];
  const float* ln3_s      = (const float*)d_in[43];
  const float* ln3_b      = (const float*)d_in[44];
  (void)in_sizes; (void)n_in; (void)out_size; (void)ws_size;

  const int R = NB*J; // 1728

  char* wp = (char*)d_ws;
  auto alloc = [&](size_t bytes)->void*{
    void* r = (void*)wp;
    wp += (bytes + 255) & ~(size_t)255;
    return r;
  };
  float*        denom_sum = (float*)alloc(R*4);
  int*          rescue    = (int*)  alloc(R*4);
  int*          allm      = (int*)  alloc(R*4);
  unsigned int* bitmap    = (unsigned int*)alloc(NB*(NP/32)*4);
  int*          act_idx   = (int*)  alloc(NB*CAP*4);
  int*          act_cnt   = (int*)  alloc(NB*4);
  int*          act_off   = (int*)  alloc(NB*4);
  int*          act_total = (int*)  alloc(64);
  float* Gp       = (float*)alloc((size_t)NB*GCH*J*64*4);
  float* G        = (float*)alloc((size_t)R*64*4);
  float* h_dop    = (float*)alloc((size_t)R*D*4);
  float* h_state  = (float*)alloc((size_t)R*D*4);
  float* h_coarse = (float*)alloc((size_t)R*D*4);
  float* hstruct  = (float*)alloc((size_t)R*D*4);
  float* xres     = (float*)alloc((size_t)R*D*4);
  float* qbuf     = (float*)alloc((size_t)R*D*4);
  float* h_time   = (float*)alloc((size_t)NB*D*4);
  float* mod2     = (float*)alloc((size_t)R*2*D*4);
  float* qkv      = (float*)alloc((size_t)R*3*D*4);
  float* kv_act   = (float*)alloc((size_t)NB*CAP*2*D*4);   // stage-1 aliases hs2 h/l
  u16* hsh   = (u16*)alloc((size_t)R*D*2);
  u16* hsl   = (u16*)alloc((size_t)R*D*2);
  u16* hbufh = (u16*)alloc((size_t)R*D*2);
  u16* hbufl = (u16*)alloc((size_t)R*D*2);
  u16* attnoh= (u16*)alloc((size_t)R*D*2);
  u16* attnol= (u16*)alloc((size_t)R*D*2);
  u16* ffhh  = (u16*)alloc((size_t)R*DFF*2);
  u16* ffhl  = (u16*)alloc((size_t)R*DFF*2);
  u16* mah   = (u16*)alloc((size_t)NB*CAP*D*2);
  u16* mal   = (u16*)alloc((size_t)NB*CAP*D*2);
  u16* time_w2t = (u16*)alloc((size_t)512*512*2);
  u16* mod_w1t  = (u16*)alloc((size_t)1024*512*2);
  u16* mod_w2t  = (u16*)alloc((size_t)1024*1024*2);
  u16* diff_wt  = (u16*)alloc((size_t)512*1024*2);
  u16* sa_qkv_t = (u16*)alloc((size_t)NLAYER*1536*512*2);
  u16* sa_out_t = (u16*)alloc((size_t)NLAYER*512*512*2);
  u16* ca_qkv_t = (u16*)alloc((size_t)NLAYER*1536*512*2);
  u16* ca_out_t = (u16*)alloc((size_t)NLAYER*512*512*2);
  u16* ff1_t    = (u16*)alloc((size_t)NLAYER*2048*512*2);
  u16* ff2_t    = (u16*)alloc((size_t)NLAYER*512*2048*2);
  // stage-1-only aliases (dead regions reused)
  u16* thh   = attnoh;                 // 64x512; dead before attn
  u16* thl   = attnol;
  u16* mod1h = ffhh;                   // Rx1024 in Rx2048; dead before ff1
  u16* mod1l = ffhl;
  u16* hs2h  = (u16*)kv_act;           // Rx1024 x2; dead before layer-0 kv
  u16* hs2l  = (u16*)kv_act + (size_t)R*2*D;

  // ---- weight conversion (once per launch) ----
  k_wconv<<<dim3(8, 8, 1),  256, 0, stream>>>(time_w2, time_w2t, 512, 512);
  k_wconv<<<dim3(8, 16, 1), 256, 0, stream>>>(mod_w1, mod_w1t, 512, 1024);
  k_wconv<<<dim3(16, 16, 1),256, 0, stream>>>(mod_w2, mod_w2t, 1024, 1024);
  k_wconv<<<dim3(16, 8, 1), 256, 0, stream>>>(diff_w, diff_wt, 1024, 512);
  k_wconv<<<dim3(8, 24, NLAYER), 256, 0, stream>>>(sa_qkv_w, sa_qkv_t, 512, 1536);
  k_wconv<<<dim3(8, 8, NLAYER),  256, 0, stream>>>(sa_out_w, sa_out_t, 512, 512);
  k_wconv<<<dim3(8, 24, NLAYER), 256, 0, stream>>>(ca_qkv_w, ca_qkv_t, 512, 1536);
  k_wconv<<<dim3(8, 8, NLAYER),  256, 0, stream>>>(ca_out_w, ca_out_t, 512, 512);
  k_wconv<<<dim3(8, 32, NLAYER), 256, 0, stream>>>(ff1_w, ff1_t, 512, 2048);
  k_wconv<<<dim3(32, 8, NLAYER), 256, 0, stream>>>(ff2_w, ff2_t, 2048, 512);

  // ---- stage 0: masks / active set / h_dop ----
  hipMemsetAsync(bitmap, 0, NB*(NP/32)*4, stream);
  k_perj<<<R, 256, 0, stream>>>(x_t, radar, denom_sum, rescue, allm, bitmap);
  k_compact<<<NB, 64, 0, stream>>>(bitmap, act_idx, act_cnt);
  k_scan<<<1, 64, 0, stream>>>(act_cnt, act_off, act_total);
  k_gpart<<<dim3(NB, GCH), 256, 0, stream>>>(x_t, radar, dop_w1, dop_b1, Gp);
  k_gred<<<R*64/256, 256, 0, stream>>>(Gp, G);
  k_hdop2<<<dim3(NB, 2), 256, 0, stream>>>(G, dop_w2, dop_b2, denom_sum, h_dop);

  // ---- stage 1: query build ----
  k_stage1<<<(2*R*D + NB*D + 255)/256, 256, 0, stream>>>(
      x_t, state_w, state_b, coarse, coarse_w, coarse_b, t_in, time_w1, time_b1,
      h_state, hsh, hsl, h_coarse, thh, thl);
  gemm(thh, thl, time_w2t, time_b2, nullptr, h_time, nullptr, nullptr, NB, 512, 512, 0, nullptr, 32, stream);
  gemm(hsh, hsl, mod_w1t, mod_b1, nullptr, nullptr, mod1h, mod1l, R, 1024, 512, 1, nullptr, 32, stream);
  gemm(mod1h, mod1l, mod_w2t, mod_b2, nullptr, mod2, nullptr, nullptr, R, 1024, 1024, 0, nullptr, 32, stream);
  k_hs2<<<(R*2*D+255)/256, 256, 0, stream>>>(h_state, hs2h, hs2l);
  gemm(hs2h, hs2l, diff_wt, diff_b, nullptr, hstruct, nullptr, nullptr, R, 512, 1024, 0, nullptr, 32, stream);
  k_query<<<(R*D+255)/256, 256, 0, stream>>>(h_coarse, h_time, h_dop, h_state, hstruct,
                                             jid_emb, mod2, xres);
  k_memact<<<NB*CAP, 128, 0, stream>>>(x_t, radar, pc_w, pc_b, act_idx, act_cnt, act_off, mah, mal);

  // ---- stage 2: transformer layers ----
  for (int l = 0; l < NLAYER; ++l){
    k_ln<<<R, 256, 0, stream>>>(xres, ln1_s + l*D, ln1_b + l*D, hbufh, hbufl);
    gemm(hbufh, hbufl, sa_qkv_t + (size_t)l*1536*512, sa_qkv_b + l*1536, nullptr,
         qkv, nullptr, nullptr, R, 1536, 512, 0, nullptr, 32, stream);
    k_selfattn<<<NB*H, 256, 0, stream>>>(qkv, attnoh, attnol);
    gemm(attnoh, attnol, sa_out_t + (size_t)l*512*512, sa_out_b + l*D, xres,
         xres, nullptr, nullptr, R, 512, 512, 0, nullptr, 32, stream);

    k_ln<<<R, 256, 0, stream>>>(xres, ln2_s + l*D, ln2_b + l*D, hbufh, hbufl);
    gemm(hbufh, hbufl, ca_qkv_t + (size_t)l*1536*512, ca_qkv_b + l*1536, nullptr,
         qbuf, nullptr, nullptr, R, 512, 512, 0, nullptr, 32, stream);
    gemm(mah, mal, ca_qkv_t + (size_t)l*1536*512 + (size_t)512*512, ca_qkv_b + l*1536 + 512,
         nullptr, kv_act, nullptr, nullptr, NB*CAP, 1024, 512, 0, act_total, 64, stream);
    k_crossattn<<<NB*H, 256, 0, stream>>>(qbuf, kv_act, x_t, radar, act_idx, act_cnt,
                                          act_off, rescue, allm, attnoh, attnol);
    gemm(attnoh, attnol, ca_out_t + (size_t)l*512*512, ca_out_b + l*D, xres,
         xres, nullptr, nullptr, R, 512, 512, 0, nullptr, 32, stream);

    k_ln<<<R, 256, 0, stream>>>(xres, ln3_s + l*D, ln3_b + l*D, hbufh, hbufl);
    gemm(hbufh, hbufl, ff1_t + (size_t)l*2048*512, ff1_b + l*DFF, nullptr,
         nullptr, ffhh, ffhl, R, 2048, 512, 2, nullptr, 32, stream);
    gemm(ffhh, ffhl, ff2_t + (size_t)l*512*2048, ff2_b + l*D, xres,
         xres, nullptr, nullptr, R, 512, 2048, 0, nullptr, 32, stream);
  }

  k_vel<<<R, 192, 0, stream>>>(xres, vel_w, vel_b, (float*)d_out);
}

// Round 6
// 1061.998 us; speedup vs baseline: 3.0610x; 1.1464x over previous
//
#include <hip/hip_runtime.h>

#define J 27
#define D 512
#define H 8
#define DH 64
#define NLAYER 6
#define DFF 2048
#define NB 64
#define NP 2048
#define CAP 128
#define GCH 16
#define GPTS 128
#define NEGF -1000000000.0f

typedef unsigned short u16;
typedef __attribute__((ext_vector_type(8))) __bf16 bf16x8;
typedef __attribute__((ext_vector_type(4))) float f32x4;

__constant__ int c_parent[J] = {0,0,1,2,3,4,5,6,7,8,8,3,11,12,13,14,15,15,0,18,19,20,0,22,23,24,3};
__constant__ float c_scale[J] = {0.6f,0.6f,0.6f,0.6f,1.f,1.f,1.f,1.f,1.f,1.5f,1.5f,1.f,1.f,1.f,1.f,1.f,
                                 1.5f,1.5f,0.6f,1.f,1.5f,1.5f,0.6f,1.f,1.5f,1.5f,1.5f};

__device__ __forceinline__ float siluf(float x){ return x/(1.f+expf(-x)); }

__device__ __forceinline__ u16 f2bf(float f){
  union { float f; unsigned u; } x; x.f = f;
  unsigned r = x.u + 0x7FFFu + ((x.u >> 16) & 1u);
  return (u16)(r >> 16);
}

// ---------- per (b,j): denom sum, rescue idx, allmask, active-bitmap marks ----------
__global__ void k_perj(const float* __restrict__ x_t, const float* __restrict__ pc,
                       float* __restrict__ denom_sum, int* __restrict__ rescue,
                       int* __restrict__ allm, unsigned int* __restrict__ bitmap){
  int bj = blockIdx.x; int b = bj / J, j = bj % J;
  int t = threadIdx.x;
  float x0 = x_t[(b*J+j)*3+0];
  float x1 = x_t[(b*J+j)*3+1];
  float x2 = x_t[(b*J+j)*3+2];
  float sx = x0*x0+x1*x1+x2*x2;
  float ar = c_scale[j]*0.1f;
  float sig = ar*0.5f;
  float twos2 = 2.f*sig*sig;
  float sum = 0.f, bmin = 3.4e38f; int bidx = NP; int any = 0;
  for (int n = t; n < NP; n += 256){
    const float* p = pc + ((size_t)b*NP + n)*6;
    float p0=p[0], p1=p[1], p2=p[2];
    float d2 = sx + (p0*p0+p1*p1+p2*p2) - 2.f*(x0*p0+x1*p1+x2*p2);
    float dist = sqrtf(fmaxf(d2, 0.f));
    sum += expf(-(dist*dist)/twos2);
    if (dist < bmin){ bmin = dist; bidx = n; }
    if (dist <= ar){ any = 1; atomicOr(&bitmap[b*(NP/32)+(n>>5)], 1u<<(n&31)); }
  }
  __shared__ float ssum[256]; __shared__ float smin[256];
  __shared__ int sidx[256]; __shared__ int sany[256];
  ssum[t]=sum; smin[t]=bmin; sidx[t]=bidx; sany[t]=any;
  __syncthreads();
  for (int s = 128; s > 0; s >>= 1){
    if (t < s){
      ssum[t] += ssum[t+s];
      if (smin[t+s] < smin[t] || (smin[t+s]==smin[t] && sidx[t+s] < sidx[t])){ smin[t]=smin[t+s]; sidx[t]=sidx[t+s]; }
      sany[t] |= sany[t+s];
    }
    __syncthreads();
  }
  if (t == 0){
    denom_sum[bj] = ssum[0];
    rescue[bj] = sidx[0];
    allm[bj] = sany[0] ? 0 : 1;
    if (!sany[0]) atomicOr(&bitmap[b*(NP/32)+(sidx[0]>>5)], 1u<<(sidx[0]&31));
  }
}

// ---------- ordered compaction of active bitmap ----------
__global__ void k_compact(const unsigned int* __restrict__ bitmap, int* __restrict__ act_idx,
                          int* __restrict__ act_cnt){
  int b = blockIdx.x; int t = threadIdx.x; // 64 = 1 wave
  unsigned int w = bitmap[b*(NP/32)+t];
  int c = __popc(w);
  int off = c;
  for (int s = 1; s < 64; s <<= 1){
    int v = __shfl_up(off, s);
    if (t >= s) off += v;
  }
  int total = __shfl(off, 63);
  off -= c;
  int base = off;
  for (int bit = 0; bit < 32; ++bit){
    if (w & (1u<<bit)){
      if (base < CAP) act_idx[b*CAP+base] = t*32+bit;
      base++;
    }
  }
  if (t == 0) act_cnt[b] = total > CAP ? CAP : total;
}

__global__ void k_scan(const int* __restrict__ act_cnt, int* __restrict__ act_off,
                       int* __restrict__ act_total){
  if (threadIdx.x == 0){
    int s = 0;
    for (int b = 0; b < NB; ++b){ act_off[b] = s; s += act_cnt[b]; }
    act_total[0] = s;
  }
}

// ---------- G[b,ch,j,h] = sum_p dws[b,j,p] * silu(dop*w1[h]+b1[h])  via MFMA ----------
// A = dws (32x128 bf16, rows j), B^T = hidT (64x128 bf16, rows h). XOR-swizzled LDS.
__launch_bounds__(256)
__global__ void k_gpart(const float* __restrict__ x_t, const float* __restrict__ pc,
                        const float* __restrict__ dop_w1, const float* __restrict__ dop_b1,
                        float* __restrict__ Gp){
  int b = blockIdx.x, ch = blockIdx.y; int t = threadIdx.x;
  __shared__ float sx[J*3];
  __shared__ float w1s[64], b1s[64];
  __shared__ float spx[GPTS], spy[GPTS], spz[GPTS], sdp[GPTS];
  __shared__ u16 hidT[64*128];   // [h][p] rows 256B
  __shared__ u16 dwsA[32*128];   // [j][p] rows 256B (rows 27-31 unused)
  if (t < J*3) sx[t] = x_t[b*J*3 + t];
  if (t < 64){ w1s[t] = dop_w1[t]; b1s[t] = dop_b1[t]; }
  int n0 = ch*GPTS;
  if (t < GPTS){
    const float* p = pc + ((size_t)b*NP + n0 + t)*6;
    float2 f0 = *(const float2*)p;
    float2 f1 = *(const float2*)(p+2);
    spx[t]=f0.x; spy[t]=f0.y; spz[t]=f1.x; sdp[t]=f1.y;
  }
  __syncthreads();
  { // hidT: h = t&63, 32 p's per thread
    int h = t & 63, pb = (t>>6)*32;
    float w1 = w1s[h], b1 = b1s[h];
    char* base = (char*)hidT;
    #pragma unroll
    for (int m = 0; m < 16; ++m){
      float v0 = siluf(sdp[pb+2*m]*w1 + b1);
      float v1 = siluf(sdp[pb+2*m+1]*w1 + b1);
      unsigned pk = (unsigned)f2bf(v0) | ((unsigned)f2bf(v1) << 16);
      int off = (h*256 + pb*2 + 4*m) ^ ((h&7)<<4);
      *(unsigned*)(base + off) = pk;
    }
  }
  { // dwsA: j = t&31 (skip j>=27), 16 p's per thread
    int j = t & 31, pb = (t>>5)*16;
    if (j < J){
      float x0=sx[j*3], x1=sx[j*3+1], x2=sx[j*3+2];
      float sxx = x0*x0+x1*x1+x2*x2;
      float sig = c_scale[j]*0.05f;
      float inv2 = 1.f/(2.f*sig*sig);
      char* base = (char*)dwsA;
      #pragma unroll
      for (int m = 0; m < 8; ++m){
        float v[2];
        #pragma unroll
        for (int u = 0; u < 2; ++u){
          int p = pb + 2*m + u;
          float p0=spx[p], p1=spy[p], p2=spz[p];
          float d2 = sxx + (p0*p0+p1*p1+p2*p2) - 2.f*(x0*p0+x1*p1+x2*p2);
          float dist = sqrtf(fmaxf(d2, 0.f));
          v[u] = expf(-(dist*dist)*inv2);
        }
        unsigned pk = (unsigned)f2bf(v[0]) | ((unsigned)f2bf(v[1]) << 16);
        int off = (j*256 + pb*2 + 4*m) ^ ((j&7)<<4);
        *(unsigned*)(base + off) = pk;
      }
    }
  }
  __syncthreads();
  // MFMA: wave w handles cols h0 = w*16; M=32 (2 frags) x K=128 (4 steps)
  int lane = t & 63, wv = t >> 6;
  int h0 = wv * 16;
  int fr = lane & 15, fkb = (lane>>4)*16;
  f32x4 acc[2] = {};
  #pragma unroll
  for (int ks = 0; ks < 4; ++ks){
    bf16x8 bfrag;
    {
      int row = h0 + fr;
      int adr = (row*256 + ks*64 + fkb) ^ ((row&7)<<4);
      bfrag = *(const bf16x8*)((char*)hidT + adr);
    }
    #pragma unroll
    for (int m = 0; m < 2; ++m){
      int row = m*16 + fr;
      int adr = (row*256 + ks*64 + fkb) ^ ((row&7)<<4);
      bf16x8 afrag = *(const bf16x8*)((char*)dwsA + adr);
      acc[m] = __builtin_amdgcn_mfma_f32_16x16x32_bf16(afrag, bfrag, acc[m], 0,0,0);
    }
  }
  float* out = Gp + ((size_t)(b*GCH+ch))*J*64;
  int er = (lane>>4)*4, ec = lane&15;
  #pragma unroll
  for (int m = 0; m < 2; ++m){
    #pragma unroll
    for (int q = 0; q < 4; ++q){
      int j = m*16 + er + q;
      if (j < J) out[j*64 + h0 + ec] = acc[m][q];
    }
  }
}

// ---------- reduce Gp chunks -> G[bj][64] ----------
__global__ void k_gred(const float* __restrict__ Gp, float* __restrict__ G){
  int idx = blockIdx.x*256 + threadIdx.x;   // < R*64
  int bj = idx >> 6, h = idx & 63;
  int b = bj / J, j = bj % J;
  float s = 0.f;
  #pragma unroll
  for (int c = 0; c < GCH; ++c) s += Gp[((size_t)(b*GCH+c)*J + j)*64 + h];
  G[idx] = s;
}

// ---------- h_dop: one block per (b, d-half); G in LDS; 27 reg accumulators ----------
__launch_bounds__(256)
__global__ void k_hdop2(const float* __restrict__ G, const float* __restrict__ dop_w2,
                        const float* __restrict__ dop_b2, const float* __restrict__ denom_sum,
                        float* __restrict__ h_dop){
  int b = blockIdx.x, half = blockIdx.y;
  int t = threadIdx.x;
  int d = half*256 + t;
  __shared__ float sG[J*64];
  __shared__ float sS[J], sI[J];
  for (int e = t; e < J*64; e += 256) sG[e] = G[(size_t)b*J*64 + e];
  if (t < J){ float S = denom_sum[b*J+t]; sS[t] = S; sI[t] = 1.f/(S+1e-6f); }
  __syncthreads();
  float acc[J];
  #pragma unroll
  for (int j = 0; j < J; ++j) acc[j] = 0.f;
  for (int h = 0; h < 64; ++h){
    float wv = dop_w2[h*D + d];
    #pragma unroll
    for (int j = 0; j < J; ++j) acc[j] += sG[j*64+h]*wv;
  }
  float b2 = dop_b2[d];
  #pragma unroll
  for (int j = 0; j < J; ++j)
    h_dop[(size_t)(b*J+j)*D + d] = (acc[j] + sS[j]*b2)*sI[j];
}

// ---------- merged stage-1 elementwise ----------
__global__ void k_stage1(const float* __restrict__ x_t, const float* __restrict__ state_w,
                         const float* __restrict__ state_b,
                         const float* __restrict__ coarse, const float* __restrict__ coarse_w,
                         const float* __restrict__ coarse_b,
                         const float* __restrict__ t_in, const float* __restrict__ time_w1,
                         const float* __restrict__ time_b1,
                         float* __restrict__ h_state, u16* __restrict__ hsh,
                         float* __restrict__ h_coarse, u16* __restrict__ thh){
  const int RD = NB*J*D;
  int idx = blockIdx.x*256 + threadIdx.x;
  if (idx < RD){
    int r = idx / D, d = idx % D;
    const float* ir = x_t + r*3;
    float v = ir[0]*state_w[d] + ir[1]*state_w[D+d] + ir[2]*state_w[2*D+d] + state_b[d];
    h_state[idx] = v;
    hsh[idx] = f2bf(v);
  } else if (idx < 2*RD){
    int k = idx - RD;
    int r = k / D, d = k % D;
    const float* ir = coarse + r*3;
    h_coarse[k] = ir[0]*coarse_w[d] + ir[1]*coarse_w[D+d] + ir[2]*coarse_w[2*D+d] + coarse_b[d];
  } else if (idx < 2*RD + NB*D){
    int k = idx - 2*RD;
    int b = k / D, d = k % D;
    float v = siluf(t_in[b]*time_w1[d] + time_b1[d]);
    thh[k] = f2bf(v);
  }
}

__global__ void k_hs2(const float* __restrict__ h_state, u16* __restrict__ oh){
  int idx = blockIdx.x*256 + threadIdx.x;
  if (idx >= NB*J*2*D) return;
  int r = idx / (2*D), c = idx % (2*D);
  int b = r / J, j = r % J;
  float v;
  if (c < D) v = h_state[(size_t)r*D + c];
  else       v = h_state[((size_t)(b*J) + c_parent[j])*D + (c-D)];
  oh[idx] = f2bf(v);
}

__global__ void k_query(const float* __restrict__ h_coarse, const float* __restrict__ h_time,
                        const float* __restrict__ h_dop, const float* __restrict__ h_state,
                        const float* __restrict__ hstruct, const float* __restrict__ jid,
                        const float* __restrict__ mod2, float* __restrict__ x){
  int idx = blockIdx.x*256 + threadIdx.x;
  if (idx >= NB*J*D) return;
  int r = idx / D, d = idx % D;
  int b = r / J, j = r % J;
  float q = h_coarse[idx] + h_time[b*D+d] + h_dop[idx] + h_state[idx] + hstruct[idx] + jid[j*D+d];
  float shift = mod2[(size_t)r*2*D + d];
  float scale = mod2[(size_t)r*2*D + D + d];
  x[idx] = q*(1.f+scale) + shift;
}

// ---------- memory rows for active points (bf16) ----------
__global__ void k_memact(const float* __restrict__ x_t, const float* __restrict__ pc,
                         const float* __restrict__ pc_w, const float* __restrict__ pc_b,
                         const int* __restrict__ act_idx, const int* __restrict__ act_cnt,
                         const int* __restrict__ act_off, u16* __restrict__ mh){
  int b = blockIdx.x / CAP, i = blockIdx.x % CAP;
  if (i >= act_cnt[b]) return;
  int n = act_idx[b*CAP+i];
  int t = threadIdx.x; // 128
  __shared__ float sdw[J];
  __shared__ float spi;
  const float* p = pc + ((size_t)b*NP+n)*6;
  if (t < J){
    float x0 = x_t[(b*J+t)*3+0], x1 = x_t[(b*J+t)*3+1], x2 = x_t[(b*J+t)*3+2];
    float p0=p[0], p1=p[1], p2=p[2];
    float d2 = (x0*x0+x1*x1+x2*x2) + (p0*p0+p1*p1+p2*p2) - 2.f*(x0*p0+x1*p1+x2*p2);
    float dist = sqrtf(fmaxf(d2,0.f));
    float sig = c_scale[t]*0.05f;
    sdw[t] = expf(-(dist*dist)/(2.f*sig*sig));
  }
  __syncthreads();
  if (t == 0){ float m = sdw[0]; for (int k = 1; k < J; ++k) m = fmaxf(m, sdw[k]); spi = m; }
  __syncthreads();
  float pi = spi;
  float p0=p[0],p1=p[1],p2=p[2],p3=p[3],p4=p[4],p5=p[5];
  int g = act_off[b] + i;
  for (int d = t; d < D; d += 128){
    float acc = pc_b[d] + p0*pc_w[d] + p1*pc_w[D+d] + p2*pc_w[2*D+d]
              + p3*pc_w[3*D+d] + p4*pc_w[4*D+d] + p5*pc_w[5*D+d];
    mh[(size_t)g*D + d] = f2bf(acc * pi);
  }
}

// ---------- weight conversion: W[K][N] fp32 -> Wt[N][K] bf16 rn ----------
__launch_bounds__(256)
__global__ void k_wconv(const float* __restrict__ W, u16* __restrict__ Wt, int K, int N){
  int k0 = blockIdx.x*64, n0 = blockIdx.y*64;
  size_t zo = (size_t)blockIdx.z*K*N;
  __shared__ float tile[64][65];
  int t = threadIdx.x;
  #pragma unroll
  for (int i = 0; i < 16; ++i){
    int idx = i*256 + t; int k = idx>>6, n = idx&63;
    tile[k][n] = W[zo + (size_t)(k0+k)*N + n0+n];
  }
  __syncthreads();
  #pragma unroll
  for (int i = 0; i < 8; ++i){
    int idx = i*256 + t; int n = idx>>5, kp = (idx&31)*2;
    unsigned pk = (unsigned)f2bf(tile[kp][n]) | ((unsigned)f2bf(tile[kp+1][n])<<16);
    *(unsigned*)&Wt[zo + (size_t)(n0+n)*K + k0+kp] = pk;
  }
}

// ---------- MFMA GEMM: C = act(Abf16 @ Wbf16 + bias [+ res]) ----------
// tile TM x 64, BK=64, 4 waves. A bf16 [M][K]; B pre-transposed bf16 [N][K].
template<int TM>
__launch_bounds__(256)
__global__ void k_gemm(const u16* __restrict__ Ag, const u16* __restrict__ Bt,
                       const float* __restrict__ bias, const float* __restrict__ res,
                       float* __restrict__ Cf, u16* __restrict__ Ch,
                       int M, int N, int K, int act,
                       const int* __restrict__ Mdev, int ntx){
  int Meff = Mdev ? *Mdev : M;
  int nwg = gridDim.x;
  int q8 = nwg>>3, r8 = nwg&7;
  int xcd = blockIdx.x&7, loc = blockIdx.x>>3;
  int wg = (xcd < r8 ? xcd*(q8+1) : r8*(q8+1)+(xcd-r8)*q8) + loc;
  int row0 = (wg % ntx)*TM, col0 = (wg / ntx)*64;
  if (row0 >= Meff) return;

  constexpr int MFR = TM/32;
  constexpr int RW  = TM/2;
  __shared__ u16 sA[TM*64], sB[64*64];
  int t = threadIdx.x;
  int lane = t&63, w = t>>6, wr = w>>1, wc = w&1;
  int sm = t>>3, kc = t&7;
  const u16* pA1 = Ag + (size_t)(row0+sm)*K + kc*8;
  const u16* pA2 = (TM==64) ? Ag + (size_t)(row0+sm+32)*K + kc*8 : pA1;
  const u16* pB1 = Bt + (size_t)(col0+sm)*K + kc*8;
  const u16* pB2 = Bt + (size_t)(col0+sm+32)*K + kc*8;
  int o1 = (sm*128 + kc*16) ^ ((sm&7)<<4);
  int o2 = ((sm+32)*128 + kc*16) ^ ((sm&7)<<4);
  uint4 ra1, ra2, rb1, rb2;
  auto gload = [&](int kt){
    ra1 = *(const uint4*)(pA1 + kt);
    if constexpr (TM==64) ra2 = *(const uint4*)(pA2 + kt);
    rb1 = *(const uint4*)(pB1 + kt);
    rb2 = *(const uint4*)(pB2 + kt);
  };
  auto stage = [&](){
    *(uint4*)((char*)sA + o1) = ra1;
    if constexpr (TM==64) *(uint4*)((char*)sA + o2) = ra2;
    *(uint4*)((char*)sB + o1) = rb1;
    *(uint4*)((char*)sB + o2) = rb2;
  };
  int fr = lane&15, fkb = (lane>>4)*16;
  f32x4 acc[MFR][2] = {};
  gload(0);
  stage();
  __syncthreads();
  for (int kt = 0; kt < K; kt += 64){
    bool nxt = kt + 64 < K;
    if (nxt) gload(kt + 64);
    #pragma unroll
    for (int kk = 0; kk < 2; ++kk){
      bf16x8 af[MFR], bf[2];
      #pragma unroll
      for (int m = 0; m < MFR; ++m){
        int row = wr*RW + m*16 + fr;
        int adr = (row*128 + kk*64 + fkb) ^ ((row&7)<<4);
        af[m] = *(const bf16x8*)((char*)sA + adr);
      }
      #pragma unroll
      for (int n = 0; n < 2; ++n){
        int rowb = wc*32 + n*16 + fr;
        int adr = (rowb*128 + kk*64 + fkb) ^ ((rowb&7)<<4);
        bf[n] = *(const bf16x8*)((char*)sB + adr);
      }
      #pragma unroll
      for (int m = 0; m < MFR; ++m)
        #pragma unroll
        for (int n = 0; n < 2; ++n)
          acc[m][n] = __builtin_amdgcn_mfma_f32_16x16x32_bf16(af[m], bf[n], acc[m][n], 0,0,0);
    }
    if (nxt){
      __syncthreads();
      stage();
      __syncthreads();
    }
  }
  int er = (lane>>4)*4, ec = lane&15;
  #pragma unroll
  for (int m = 0; m < MFR; ++m){
    #pragma unroll
    for (int qq = 0; qq < 4; ++qq){
      int r = row0 + wr*RW + m*16 + er + qq;
      if (r >= Meff) continue;
      #pragma unroll
      for (int n = 0; n < 2; ++n){
        int c = col0 + wc*32 + n*16 + ec;
        float v = acc[m][n][qq] + bias[c];
        if (res) v += res[(size_t)r*N + c];
        if (act == 1) v = v/(1.f+expf(-v));
        else if (act == 2) v = fmaxf(v, 0.f);
        if (Cf) Cf[(size_t)r*N + c] = v;
        if (Ch) Ch[(size_t)r*N + c] = f2bf(v);
      }
    }
  }
}

// ---------- LayerNorm over D, per row -> bf16 ----------
__global__ void k_ln(const float* __restrict__ x, const float* __restrict__ s,
                     const float* __restrict__ bb, u16* __restrict__ oh){
  int r = blockIdx.x; int t = threadIdx.x; // 256
  const float* xr = x + (size_t)r*D;
  float v0 = xr[t], v1 = xr[t+256];
  __shared__ float red[256];
  red[t] = v0+v1; __syncthreads();
  for (int st = 128; st > 0; st >>= 1){ if (t < st) red[t] += red[t+st]; __syncthreads(); }
  float mu = red[0]/(float)D;
  __syncthreads();
  float d0 = v0-mu, d1 = v1-mu;
  red[t] = d0*d0 + d1*d1; __syncthreads();
  for (int st = 128; st > 0; st >>= 1){ if (t < st) red[t] += red[t+st]; __syncthreads(); }
  float var = red[0]/(float)D;
  float rs = rsqrtf(var + 1e-5f);
  oh[(size_t)r*D + t]       = f2bf(d0*rs*s[t]       + bb[t]);
  oh[(size_t)r*D + t + 256] = f2bf(d1*rs*s[t+256]   + bb[t+256]);
}

// ---------- self-attn ----------
__launch_bounds__(256)
__global__ void k_selfattn(const float* __restrict__ qkv, u16* __restrict__ oh){
  int bh = blockIdx.x; int b = bh / H, h = bh % H;
  int t = threadIdx.x;
  __shared__ float qs[J*DH], ks[J*DH], vs[J*DH];
  __shared__ float ss[J*J];
  for (int e = t; e < J*DH; e += 256){
    int j = e/DH, d = e%DH;
    const float* base = qkv + (size_t)(b*J+j)*1536 + h*DH + d;
    qs[e] = base[0]; ks[e] = base[512]; vs[e] = base[1024];
  }
  __syncthreads();
  for (int e = t; e < J*J; e += 256){
    int qj = e/J, kk = e%J;
    float acc = 0.f;
    for (int d = 0; d < DH; ++d) acc += qs[qj*DH+d]*ks[kk*DH+d];
    float bias = (qj==kk || c_parent[qj]==kk || c_parent[kk]==qj) ? 0.f : NEGF;
    ss[e] = acc*0.125f + bias;
  }
  __syncthreads();
  if (t < J){
    float m = -3.4e38f;
    for (int k = 0; k < J; ++k) m = fmaxf(m, ss[t*J+k]);
    float sum = 0.f;
    for (int k = 0; k < J; ++k){ float e_ = expf(ss[t*J+k]-m); ss[t*J+k] = e_; sum += e_; }
    float inv = 1.f/sum;
    for (int k = 0; k < J; ++k) ss[t*J+k] *= inv;
  }
  __syncthreads();
  for (int e = t; e < J*DH; e += 256){
    int j = e/DH, d = e%DH;
    float acc = 0.f;
    for (int k = 0; k < J; ++k) acc += ss[j*J+k]*vs[k*DH+d];
    oh[(size_t)(b*J+j)*D + h*DH + d] = f2bf(acc);
  }
}

// ---------- cross-attn over active points ----------
__launch_bounds__(256)
__global__ void k_crossattn(const float* __restrict__ qbuf, const float* __restrict__ kv_act,
                            const float* __restrict__ x_t, const float* __restrict__ pc,
                            const int* __restrict__ act_idx, const int* __restrict__ act_cnt,
                            const int* __restrict__ act_off, const int* __restrict__ rescue,
                            const int* __restrict__ allm, u16* __restrict__ oh){
  int bh = blockIdx.x; int b = bh / H, h = bh % H;
  int t = threadIdx.x;
  int cnt = act_cnt[b], off = act_off[b];
  __shared__ float qs[J*DH];
  __shared__ float ks[CAP*DH];
  __shared__ float pxyz[CAP*3];
  __shared__ float sx[J*3];
  __shared__ int sn[CAP];
  __shared__ float ss[J*CAP];
  if (t < J*3) sx[t] = x_t[b*J*3+t];
  for (int e = t; e < J*DH; e += 256)
    qs[e] = qbuf[(size_t)(b*J + e/DH)*D + h*DH + (e%DH)];
  for (int e = t; e < cnt*DH; e += 256){
    int i = e/DH, d = e%DH;
    ks[e] = kv_act[(size_t)(off+i)*1024 + h*DH + d];
  }
  for (int i = t; i < cnt; i += 256){
    int n = act_idx[b*CAP+i]; sn[i] = n;
    const float* p = pc + ((size_t)b*NP+n)*6;
    pxyz[i*3] = p[0]; pxyz[i*3+1] = p[1]; pxyz[i*3+2] = p[2];
  }
  __syncthreads();
  for (int e = t; e < J*cnt; e += 256){
    int j = e/cnt, i = e%cnt;
    float acc = 0.f;
    for (int d = 0; d < DH; ++d) acc += qs[j*DH+d]*ks[i*DH+d];
    float bias;
    if (allm[b*J+j]) bias = (sn[i] == rescue[b*J+j]) ? 0.f : NEGF;
    else {
      float x0=sx[j*3], x1=sx[j*3+1], x2=sx[j*3+2];
      float p0=pxyz[i*3], p1=pxyz[i*3+1], p2=pxyz[i*3+2];
      float d2 = (x0*x0+x1*x1+x2*x2) + (p0*p0+p1*p1+p2*p2) - 2.f*(x0*p0+x1*p1+x2*p2);
      float dist = sqrtf(fmaxf(d2,0.f));
      float ar = c_scale[j]*0.1f;
      bias = (dist > ar) ? NEGF : 0.f;
    }
    ss[j*CAP+i] = acc*0.125f + bias;
  }
  __syncthreads();
  if (t < J){
    float m = -3.4e38f;
    for (int i = 0; i < cnt; ++i) m = fmaxf(m, ss[t*CAP+i]);
    float sum = 0.f;
    for (int i = 0; i < cnt; ++i){ float e_ = expf(ss[t*CAP+i]-m); ss[t*CAP+i] = e_; sum += e_; }
    float inv = 1.f/sum;
    for (int i = 0; i < cnt; ++i) ss[t*CAP+i] *= inv;
  }
  __syncthreads();
  for (int e = t; e < J*DH; e += 256){
    int j = e/DH, d = e%DH;
    float acc = 0.f;
    for (int i = 0; i < cnt; ++i)
      acc += ss[j*CAP+i]*kv_act[(size_t)(off+i)*1024 + 512 + h*DH + d];
    oh[(size_t)(b*J+j)*D + h*DH + d] = f2bf(acc);
  }
}

// ---------- final vel projection ----------
__global__ void k_vel(const float* __restrict__ x, const float* __restrict__ vel_w,
                      const float* __restrict__ vel_b, float* __restrict__ out){
  int r = blockIdx.x; int t = threadIdx.x; // 192
  int c = t >> 6; int lane = t & 63;
  float acc = 0.f;
  const float* xr = x + (size_t)r*D;
  for (int d = lane; d < D; d += 64) acc += xr[d]*vel_w[d*3+c];
  for (int s = 32; s > 0; s >>= 1) acc += __shfl_down(acc, s);
  if (lane == 0) out[r*3+c] = acc + vel_b[c];
}

// ============================================================================
static void gemm(const u16* Ah, const u16* Bt, const float* bias,
                 const float* res, float* Cf, u16* Ch,
                 int M, int N, int K, int act, const int* Mdev, int tm, hipStream_t s){
  if (tm == 32){
    int ntx = (M + 31) / 32;
    k_gemm<32><<<ntx*(N/64), 256, 0, s>>>(Ah, Bt, bias, res, Cf, Ch, M, N, K, act, Mdev, ntx);
  } else {
    int ntx = (M + 63) / 64;
    k_gemm<64><<<ntx*(N/64), 256, 0, s>>>(Ah, Bt, bias, res, Cf, Ch, M, N, K, act, Mdev, ntx);
  }
}

extern "C" void kernel_launch(void* const* d_in, const int* in_sizes, int n_in,
                              void* d_out, int out_size, void* d_ws, size_t ws_size,
                              hipStream_t stream){
  const float* x_t        = (const float*)d_in[0];
  const float* t_in       = (const float*)d_in[1];
  const float* coarse     = (const float*)d_in[2];
  const float* radar      = (const float*)d_in[3];
  const float* pc_w       = (const float*)d_in[4];
  const float* pc_b       = (const float*)d_in[5];
  const float* coarse_w   = (const float*)d_in[6];
  const float* coarse_b   = (const float*)d_in[7];
  const float* state_w    = (const float*)d_in[8];
  const float* state_b    = (const float*)d_in[9];
  const float* jid_emb    = (const float*)d_in[10];
  const float* dop_w1     = (const float*)d_in[11];
  const float* dop_b1     = (const float*)d_in[12];
  const float* dop_w2     = (const float*)d_in[13];
  const float* dop_b2     = (const float*)d_in[14];
  const float* time_w1    = (const float*)d_in[15];
  const float* time_b1    = (const float*)d_in[16];
  const float* time_w2    = (const float*)d_in[17];
  const float* time_b2    = (const float*)d_in[18];
  const float* mod_w1     = (const float*)d_in[19];
  const float* mod_b1     = (const float*)d_in[20];
  const float* mod_w2     = (const float*)d_in[21];
  const float* mod_b2     = (const float*)d_in[22];
  const float* diff_w     = (const float*)d_in[23];
  const float* diff_b     = (const float*)d_in[24];
  const float* vel_w      = (const float*)d_in[25];
  const float* vel_b      = (const float*)d_in[26];
  const float* sa_qkv_w   = (const float*)d_in[27];
  const float* sa_qkv_b   = (const float*)d_in[28];
  const float* sa_out_w   = (const float*)d_in[29];
  const float* sa_out_b   = (const float*)d_in[30];
  const float* ca_qkv_w   = (const float*)d_in[31];
  const float* ca_qkv_b   = (const float*)d_in[32];
  const float* ca_out_w   = (const float*)d_in[33];
  const float* ca_out_b   = (const float*)d_in[34];
  const float* ff1_w      = (const float*)d_in[35];
  const float* ff1_b      = (const float*)d_in[36];
  const float* ff2_w      = (const float*)d_in[37];
  const float* ff2_b      = (const float*)d_in[38];
  const float* ln1_s      = (const float*)d_in[39];
  const float* ln1_b      = (const float*)d_in[40];
  const float* ln2_s      = (const float*)d_in[41];
  const float* ln2_b      = (const float*)d_in[42];
  const float* ln3_s      = (const float*)d_in[43];
  const float* ln3_b      = (const float*)d_in[44];
  (void)in_sizes; (void)n_in; (void)out_size; (void)ws_size;

  const int R = NB*J; // 1728

  char* wp = (char*)d_ws;
  auto alloc = [&](size_t bytes)->void*{
    void* r = (void*)wp;
    wp += (bytes + 255) & ~(size_t)255;
    return r;
  };
  float*        denom_sum = (float*)alloc(R*4);
  int*          rescue    = (int*)  alloc(R*4);
  int*          allm      = (int*)  alloc(R*4);
  unsigned int* bitmap    = (unsigned int*)alloc(NB*(NP/32)*4);
  int*          act_idx   = (int*)  alloc(NB*CAP*4);
  int*          act_cnt   = (int*)  alloc(NB*4);
  int*          act_off   = (int*)  alloc(NB*4);
  int*          act_total = (int*)  alloc(64);
  float* Gp       = (float*)alloc((size_t)NB*GCH*J*64*4);
  float* G        = (float*)alloc((size_t)R*64*4);
  float* h_dop    = (float*)alloc((size_t)R*D*4);
  float* h_state  = (float*)alloc((size_t)R*D*4);
  float* h_coarse = (float*)alloc((size_t)R*D*4);
  float* hstruct  = (float*)alloc((size_t)R*D*4);
  float* xres     = (float*)alloc((size_t)R*D*4);
  float* qbuf     = (float*)alloc((size_t)R*D*4);
  float* h_time   = (float*)alloc((size_t)NB*D*4);
  float* mod2     = (float*)alloc((size_t)R*2*D*4);
  float* qkv      = (float*)alloc((size_t)R*3*D*4);
  float* kv_act   = (float*)alloc((size_t)NB*CAP*2*D*4);   // stage-1 aliases hs2
  u16* hsh   = (u16*)alloc((size_t)R*D*2);
  u16* hbufh = (u16*)alloc((size_t)R*D*2);
  u16* attnoh= (u16*)alloc((size_t)R*D*2);
  u16* ffhh  = (u16*)alloc((size_t)R*DFF*2);
  u16* mah   = (u16*)alloc((size_t)NB*CAP*D*2);
  u16* time_w2t = (u16*)alloc((size_t)512*512*2);
  u16* mod_w1t  = (u16*)alloc((size_t)1024*512*2);
  u16* mod_w2t  = (u16*)alloc((size_t)1024*1024*2);
  u16* diff_wt  = (u16*)alloc((size_t)512*1024*2);
  u16* sa_qkv_t = (u16*)alloc((size_t)NLAYER*1536*512*2);
  u16* sa_out_t = (u16*)alloc((size_t)NLAYER*512*512*2);
  u16* ca_qkv_t = (u16*)alloc((size_t)NLAYER*1536*512*2);
  u16* ca_out_t = (u16*)alloc((size_t)NLAYER*512*512*2);
  u16* ff1_t    = (u16*)alloc((size_t)NLAYER*2048*512*2);
  u16* ff2_t    = (u16*)alloc((size_t)NLAYER*512*2048*2);
  // stage-1-only aliases (dead regions reused)
  u16* thh   = attnoh;                 // 64x512; dead before attn
  u16* mod1h = ffhh;                   // Rx1024 in Rx2048; dead before ff1
  u16* hs2h  = (u16*)kv_act;           // Rx1024; dead before layer-0 kv

  // ---- weight conversion (once per launch) ----
  k_wconv<<<dim3(8, 8, 1),  256, 0, stream>>>(time_w2, time_w2t, 512, 512);
  k_wconv<<<dim3(8, 16, 1), 256, 0, stream>>>(mod_w1, mod_w1t, 512, 1024);
  k_wconv<<<dim3(16, 16, 1),256, 0, stream>>>(mod_w2, mod_w2t, 1024, 1024);
  k_wconv<<<dim3(16, 8, 1), 256, 0, stream>>>(diff_w, diff_wt, 1024, 512);
  k_wconv<<<dim3(8, 24, NLAYER), 256, 0, stream>>>(sa_qkv_w, sa_qkv_t, 512, 1536);
  k_wconv<<<dim3(8, 8, NLAYER),  256, 0, stream>>>(sa_out_w, sa_out_t, 512, 512);
  k_wconv<<<dim3(8, 24, NLAYER), 256, 0, stream>>>(ca_qkv_w, ca_qkv_t, 512, 1536);
  k_wconv<<<dim3(8, 8, NLAYER),  256, 0, stream>>>(ca_out_w, ca_out_t, 512, 512);
  k_wconv<<<dim3(8, 32, NLAYER), 256, 0, stream>>>(ff1_w, ff1_t, 512, 2048);
  k_wconv<<<dim3(32, 8, NLAYER), 256, 0, stream>>>(ff2_w, ff2_t, 2048, 512);

  // ---- stage 0: masks / active set / h_dop ----
  hipMemsetAsync(bitmap, 0, NB*(NP/32)*4, stream);
  k_perj<<<R, 256, 0, stream>>>(x_t, radar, denom_sum, rescue, allm, bitmap);
  k_compact<<<NB, 64, 0, stream>>>(bitmap, act_idx, act_cnt);
  k_scan<<<1, 64, 0, stream>>>(act_cnt, act_off, act_total);
  k_gpart<<<dim3(NB, GCH), 256, 0, stream>>>(x_t, radar, dop_w1, dop_b1, Gp);
  k_gred<<<R*64/256, 256, 0, stream>>>(Gp, G);
  k_hdop2<<<dim3(NB, 2), 256, 0, stream>>>(G, dop_w2, dop_b2, denom_sum, h_dop);

  // ---- stage 1: query build ----
  k_stage1<<<(2*R*D + NB*D + 255)/256, 256, 0, stream>>>(
      x_t, state_w, state_b, coarse, coarse_w, coarse_b, t_in, time_w1, time_b1,
      h_state, hsh, h_coarse, thh);
  gemm(thh, time_w2t, time_b2, nullptr, h_time, nullptr, NB, 512, 512, 0, nullptr, 32, stream);
  gemm(hsh, mod_w1t, mod_b1, nullptr, nullptr, mod1h, R, 1024, 512, 1, nullptr, 32, stream);
  gemm(mod1h, mod_w2t, mod_b2, nullptr, mod2, nullptr, R, 1024, 1024, 0, nullptr, 32, stream);
  k_hs2<<<(R*2*D+255)/256, 256, 0, stream>>>(h_state, hs2h);
  gemm(hs2h, diff_wt, diff_b, nullptr, hstruct, nullptr, R, 512, 1024, 0, nullptr, 32, stream);
  k_query<<<(R*D+255)/256, 256, 0, stream>>>(h_coarse, h_time, h_dop, h_state, hstruct,
                                             jid_emb, mod2, xres);
  k_memact<<<NB*CAP, 128, 0, stream>>>(x_t, radar, pc_w, pc_b, act_idx, act_cnt, act_off, mah);

  // ---- stage 2: transformer layers ----
  for (int l = 0; l < NLAYER; ++l){
    k_ln<<<R, 256, 0, stream>>>(xres, ln1_s + l*D, ln1_b + l*D, hbufh);
    gemm(hbufh, sa_qkv_t + (size_t)l*1536*512, sa_qkv_b + l*1536, nullptr,
         qkv, nullptr, R, 1536, 512, 0, nullptr, 32, stream);
    k_selfattn<<<NB*H, 256, 0, stream>>>(qkv, attnoh);
    gemm(attnoh, sa_out_t + (size_t)l*512*512, sa_out_b + l*D, xres,
         xres, nullptr, R, 512, 512, 0, nullptr, 32, stream);

    k_ln<<<R, 256, 0, stream>>>(xres, ln2_s + l*D, ln2_b + l*D, hbufh);
    gemm(hbufh, ca_qkv_t + (size_t)l*1536*512, ca_qkv_b + l*1536, nullptr,
         qbuf, nullptr, R, 512, 512, 0, nullptr, 32, stream);
    gemm(mah, ca_qkv_t + (size_t)l*1536*512 + (size_t)512*512, ca_qkv_b + l*1536 + 512,
         nullptr, kv_act, nullptr, NB*CAP, 1024, 512, 0, act_total, 64, stream);
    k_crossattn<<<NB*H, 256, 0, stream>>>(qbuf, kv_act, x_t, radar, act_idx, act_cnt,
                                          act_off, rescue, allm, attnoh);
    gemm(attnoh, ca_out_t + (size_t)l*512*512, ca_out_b + l*D, xres,
         xres, nullptr, R, 512, 512, 0, nullptr, 32, stream);

    k_ln<<<R, 256, 0, stream>>>(xres, ln3_s + l*D, ln3_b + l*D, hbufh);
    gemm(hbufh, ff1_t + (size_t)l*2048*512, ff1_b + l*DFF, nullptr,
         nullptr, ffhh, R, 2048, 512, 2, nullptr, 32, stream);
    gemm(ffhh, ff2_t + (size_t)l*512*2048, ff2_b + l*D, xres,
         xres, nullptr, R, 512, 2048, 0, nullptr, 32, stream);
  }

  k_vel<<<R, 192, 0, stream>>>(xres, vel_w, vel_b, (float*)d_out);
}